// Round 15
// baseline (5753.700 us; speedup 1.0000x reference)
//
#include <hip/hip_runtime.h>
#include <stdint.h>

// DCRNN forward, MI355X — R15: FUSED CELL (one barrier per GRU cell, 48 total).
//  Each block computes gates r for ALL 256 rows redundantly (xsT is fully
//  staged anyway; r is bit-identical across blocks), forms r*h IN PLACE in
//  xsT, and runs cand immediately: the r*h exchange + 48 barriers + RH
//  buffers are eliminated. Identity slice = 5th hop with A0 = I (bf16-exact),
//  so no LDS transposes; Hbuf is double-buffered with parity (rq*5+m)&1 ->
//  one sync per hop+proj phase.
//  - 256 blocks x 512 thr = 64 batches x 4 quadrants; LDS 102400 B -> 1
//    block/CU -> co-residency forced; per-batch 4-block barrier (relaxed
//    agent atomics; blocks of a batch share blockIdx%8 -> same XCD).
//  - State exchange: 8B agent-scope atomic stores/loads (R5/R13-proven path).
//  - h/u in MFMA-fragment registers; GRU epilogue fused.

typedef short short8 __attribute__((ext_vector_type(8)));
typedef float f32x4 __attribute__((ext_vector_type(4)));
typedef unsigned short ushort4v __attribute__((ext_vector_type(4)));
typedef unsigned long long u64;
typedef u64 u64x2 __attribute__((ext_vector_type(2)));

#define DEVI __device__ __forceinline__

DEVI unsigned short f2bf(float x) {
  unsigned int u = __builtin_bit_cast(unsigned int, x);
  u += 0x7FFFu + ((u >> 16) & 1u);  // RNE
  return (unsigned short)(u >> 16);
}
DEVI float bf2f(unsigned short s) {
  return __builtin_bit_cast(float, (unsigned int)s << 16);
}
DEVI u64 ald(const u64* p) { return __hip_atomic_load(p, __ATOMIC_RELAXED, __HIP_MEMORY_SCOPE_AGENT); }
DEVI void ast(u64* p, u64 v) { __hip_atomic_store(p, v, __ATOMIC_RELAXED, __HIP_MEMORY_SCOPE_AGENT); }
DEVI float aldf(const float* p) { return __hip_atomic_load(p, __ATOMIC_RELAXED, __HIP_MEMORY_SCOPE_AGENT); }
DEVI void astf(float* p, float v) { __hip_atomic_store(p, v, __ATOMIC_RELAXED, __HIP_MEMORY_SCOPE_AGENT); }

struct KP {
  const float* enc_in;
  const float* sup0; const float* sup1;
  const float* Wsrc[8];
  const float* bias[8];
  const float* prW; const float* prB;
  float* out;
  unsigned short* A5;       // [5][256][256] bf16: I, S0, 2S0^2-I, S1, 2S1^2-I
  unsigned short* Wp[8];    // packed [O][5*FP] bf16 (m=0 = identity slice)
  unsigned short* H0[2];    // [64 b][64 f][256 n] bf16 rows, ping-pong
  unsigned short* H1[2];
  float* XD;                // [64][256] decoder feedback
  unsigned* ctr;            // 64 per-batch counters, 256B apart
};

// ---------------- prep kernel (512 blocks x 256) ----------------
__global__ void prep(KP p) {
  const int i = blockIdx.x, tid = threadIdx.x;
  {  // A5 matrices (m0 = exact bf16 identity)
    const int s = i & 1, r = i >> 1;
    const float* S = s ? p.sup1 : p.sup0;
    float acc = 0.f;
    for (int k = 0; k < 256; ++k) acc = fmaf(S[r * 256 + k], S[k * 256 + tid], acc);
    if (s == 0) p.A5[r * 256 + tid] = (r == tid) ? (unsigned short)0x3F80 : (unsigned short)0;
    p.A5[(1 + 2 * s) * 65536 + r * 256 + tid] = f2bf(S[r * 256 + tid]);
    p.A5[(2 + 2 * s) * 65536 + r * 256 + tid] = f2bf(2.f * acc - (r == tid ? 1.f : 0.f));
  }
  {  // packed weights: Wp[o][m*FP+f] = W[f,m,o], f zero-padded to FP
    const int gtid = i * 256 + tid;
    const int Fs[8]  = {66, 66, 128, 128, 65, 65, 128, 128};
    const int Os[8]  = {128, 64, 128, 64, 128, 64, 128, 64};
    const int FPs[8] = {96, 96, 128, 128, 96, 96, 128, 128};
    for (int w = 0; w < 8; ++w) {
      const int FPw = FPs[w], KPw = 5 * FPw, tot = Os[w] * KPw;
      for (int e = gtid; e < tot; e += 512 * 256) {
        const int o = e / KPw, k2 = e - o * KPw, m = k2 / FPw, f = k2 - m * FPw;
        p.Wp[w][e] = f2bf((f < Fs[w]) ? p.Wsrc[w][(f * 5 + m) * Os[w] + o] : 0.f);
      }
    }
  }
  {  // zero initial hidden via agent-scope stores
    const int gtid = i * 256 + tid;
    u64* z0 = (u64*)p.H0[0];
    u64* z1 = (u64*)p.H1[0];
    ast(z0 + 2 * gtid, 0); ast(z0 + 2 * gtid + 1, 0);
    ast(z1 + 2 * gtid, 0); ast(z1 + 2 * gtid + 1, 0);
  }
  if (i == 0 && tid < 64)
    __hip_atomic_store(p.ctr + tid * 64, 0u, __ATOMIC_RELAXED, __HIP_MEMORY_SCOPE_AGENT);
}

// ---------------- fused GRU cell (gates full-row + cand, one barrier) ----------------
// MODE 1: normal cell; MODE 2: + final decoder projection (out slice, XD)
template<int IND, int FP, int MODE>
DEVI void cell_stage(int b, int q, int n0, int tid,
                     const float* xf32,            // IND==2: enc x; IND==1: XD (or null)
                     const unsigned short* xbf,    // IND==64: x rows (layer-0 H)
                     const unsigned short* hrows,  // own-layer h rows [64 f][256 n]
                     const unsigned short* A5,
                     const unsigned short* Wg, const float* bg,
                     const unsigned short* Wc, const float* bc,
                     f32x4 (&hreg)[2],
                     unsigned short* hout,
                     const float* projW, const float* projB,
                     float* outp, float* xdout,
                     unsigned short* xsT, unsigned short* Hbuf)
{
  constexpr int KPW = 5 * FP;
  constexpr int XS = 264;            // xsT row stride (bf16 elems)
  constexpr int HS = 136;            // Hbuf row stride
  constexpr int HB = 64 * HS;        // one Hbuf buffer
  constexpr int NFT = FP / 16;

  const int wv = tid >> 6, ln = tid & 63;
  const int l15 = ln & 15, l4 = ln >> 4;
  const int wr = wv & 1, wc = wv >> 1;   // row-half / tile-column quarter
  const int r0 = wr * 32;

  // ---- stage xsT [f][n]: h + x (agent-scope u64 loads) ----
  {
    u64 la[4], lb[4];
    const u64* src = (const u64*)hrows;
#pragma unroll
    for (int it = 0; it < 4; ++it) {
      const int g = tid + it * 512;
      la[it] = ald(src + 2 * g); lb[it] = ald(src + 2 * g + 1);
    }
#pragma unroll
    for (int it = 0; it < 4; ++it) {
      const int g = tid + it * 512, row = g >> 5, c = g & 31;
      u64x2 v; v[0] = la[it]; v[1] = lb[it];
      *reinterpret_cast<u64x2*>(&xsT[(IND + row) * XS + c * 8]) = v;
    }
    if (IND == 64) {
      u64 xa[4], xb2[4];
      const u64* src2 = (const u64*)xbf;
#pragma unroll
      for (int it = 0; it < 4; ++it) {
        const int g = tid + it * 512;
        xa[it] = ald(src2 + 2 * g); xb2[it] = ald(src2 + 2 * g + 1);
      }
#pragma unroll
      for (int it = 0; it < 4; ++it) {
        const int g = tid + it * 512, row = g >> 5, c = g & 31;
        u64x2 v; v[0] = xa[it]; v[1] = xb2[it];
        *reinterpret_cast<u64x2*>(&xsT[row * XS + c * 8]) = v;
      }
    } else if (IND == 2) {
      xsT[(tid & 1) * XS + (tid >> 1)] = f2bf(xf32[tid]);
    } else {  // IND == 1 (decoder feedback)
      if (tid < 256) xsT[tid] = xf32 ? f2bf(aldf(xf32 + tid)) : (unsigned short)0;
    }
    // pads [IND+64, FP) zeroed once in prologue; only finite bf16 ever written;
    // Wp zero pad columns annihilate stale values (R13-proven).
  }
  __syncthreads();

  // ---- GATES: r for all 256 rows (redundant per block), u for own rows ----
  f32x4 pr[4][2], pu[2];
#pragma unroll
  for (int rq = 0; rq < 4; ++rq)
#pragma unroll
    for (int rt = 0; rt < 2; ++rt) pr[rq][rt] = 0.f;
#pragma unroll
  for (int rt = 0; rt < 2; ++rt) pu[rt] = 0.f;

#pragma unroll
  for (int rq = 0; rq < 4; ++rq) {
    for (int m = 0; m < 5; ++m) {              // m=0 is identity hop (A0 = I)
      const unsigned short* Am = A5 + m * 65536;
      f32x4 hacc[2][2];
#pragma unroll
      for (int rt = 0; rt < 2; ++rt) { hacc[rt][0] = 0.f; hacc[rt][1] = 0.f; }
#pragma unroll
      for (int k0 = 0; k0 < 256; k0 += 32) {
        short8 af[2];
#pragma unroll
        for (int rt = 0; rt < 2; ++rt)
          af[rt] = *reinterpret_cast<const short8*>(&Am[(rq * 64 + r0 + rt * 16 + l15) * 256 + k0 + l4 * 8]);
#pragma unroll
        for (int fi = 0; fi < 2; ++fi) {
          const int ft = wc + 4 * fi;
          if (ft < NFT) {
            short8 bf = *reinterpret_cast<const short8*>(&xsT[(ft * 16 + l15) * XS + k0 + l4 * 8]);
#pragma unroll
            for (int rt = 0; rt < 2; ++rt)
              hacc[rt][fi] = __builtin_amdgcn_mfma_f32_16x16x32_bf16(af[rt], bf, hacc[rt][fi], 0, 0, 0);
          }
        }
      }
      unsigned short* dst = Hbuf + ((rq * 5 + m) & 1) * HB;
#pragma unroll
      for (int fi = 0; fi < 2; ++fi) {
        const int ft = wc + 4 * fi;
        if (ft < NFT) {
#pragma unroll
          for (int rt = 0; rt < 2; ++rt)
#pragma unroll
            for (int j = 0; j < 4; ++j)
              dst[(r0 + rt * 16 + l4 * 4 + j) * HS + ft * 16 + l15] = f2bf(hacc[rt][fi][j]);
        }
      }
      __syncthreads();
      // proj m: r-tile wc for quadrant rq (+ u-tile 4+wc if own quadrant)
#pragma unroll
      for (int k0 = 0; k0 < FP; k0 += 32) {
        short8 af2[2];
#pragma unroll
        for (int rt = 0; rt < 2; ++rt)
          af2[rt] = *reinterpret_cast<const short8*>(&dst[(r0 + rt * 16 + l15) * HS + k0 + l4 * 8]);
        short8 bfr = *reinterpret_cast<const short8*>(&Wg[(wc * 16 + l15) * KPW + m * FP + k0 + l4 * 8]);
#pragma unroll
        for (int rt = 0; rt < 2; ++rt)
          pr[rq][rt] = __builtin_amdgcn_mfma_f32_16x16x32_bf16(af2[rt], bfr, pr[rq][rt], 0, 0, 0);
        if (rq == q) {
          short8 bfu = *reinterpret_cast<const short8*>(&Wg[((4 + wc) * 16 + l15) * KPW + m * FP + k0 + l4 * 8]);
#pragma unroll
          for (int rt = 0; rt < 2; ++rt)
            pu[rt] = __builtin_amdgcn_mfma_f32_16x16x32_bf16(af2[rt], bfu, pu[rt], 0, 0, 0);
        }
      }
    }
  }

  // ---- r*h in place (all rows); u to regs (own rows) ----
  const float br = bg[wc * 16 + l15];
  const float bu = bg[64 + wc * 16 + l15];
  f32x4 u[2];
#pragma unroll
  for (int rt = 0; rt < 2; ++rt)
#pragma unroll
    for (int jj = 0; jj < 4; ++jj)
      u[rt][jj] = 1.f / (1.f + __expf(-(pu[rt][jj] + bu)));
#pragma unroll
  for (int rq = 0; rq < 4; ++rq)
#pragma unroll
    for (int rt = 0; rt < 2; ++rt) {
      unsigned short* ap = &xsT[(IND + wc * 16 + l15) * XS + rq * 64 + r0 + rt * 16 + l4 * 4];
      ushort4v hv = *reinterpret_cast<ushort4v*>(ap);
      ushort4v pk;
#pragma unroll
      for (int jj = 0; jj < 4; ++jj) {
        const float r = 1.f / (1.f + __expf(-(pr[rq][rt][jj] + br)));
        pk[jj] = f2bf(r * bf2f(hv[jj]));
      }
      *reinterpret_cast<ushort4v*>(ap) = pk;
    }
  __syncthreads();

  // ---- CAND (own 64 rows), xsT now holds [x, r*h] ----
  f32x4 pc[2];
#pragma unroll
  for (int rt = 0; rt < 2; ++rt) pc[rt] = 0.f;
  for (int m = 0; m < 5; ++m) {
    const unsigned short* Am = A5 + m * 65536;
    f32x4 hacc[2][2];
#pragma unroll
    for (int rt = 0; rt < 2; ++rt) { hacc[rt][0] = 0.f; hacc[rt][1] = 0.f; }
#pragma unroll
    for (int k0 = 0; k0 < 256; k0 += 32) {
      short8 af[2];
#pragma unroll
      for (int rt = 0; rt < 2; ++rt)
        af[rt] = *reinterpret_cast<const short8*>(&Am[(n0 + r0 + rt * 16 + l15) * 256 + k0 + l4 * 8]);
#pragma unroll
      for (int fi = 0; fi < 2; ++fi) {
        const int ft = wc + 4 * fi;
        if (ft < NFT) {
          short8 bf = *reinterpret_cast<const short8*>(&xsT[(ft * 16 + l15) * XS + k0 + l4 * 8]);
#pragma unroll
          for (int rt = 0; rt < 2; ++rt)
            hacc[rt][fi] = __builtin_amdgcn_mfma_f32_16x16x32_bf16(af[rt], bf, hacc[rt][fi], 0, 0, 0);
        }
      }
    }
    unsigned short* dst = Hbuf + (m & 1) * HB;
#pragma unroll
    for (int fi = 0; fi < 2; ++fi) {
      const int ft = wc + 4 * fi;
      if (ft < NFT) {
#pragma unroll
        for (int rt = 0; rt < 2; ++rt)
#pragma unroll
          for (int j = 0; j < 4; ++j)
            dst[(r0 + rt * 16 + l4 * 4 + j) * HS + ft * 16 + l15] = f2bf(hacc[rt][fi][j]);
      }
    }
    __syncthreads();
#pragma unroll
    for (int k0 = 0; k0 < FP; k0 += 32) {
      short8 af2[2];
#pragma unroll
      for (int rt = 0; rt < 2; ++rt)
        af2[rt] = *reinterpret_cast<const short8*>(&dst[(r0 + rt * 16 + l15) * HS + k0 + l4 * 8]);
      short8 bfc = *reinterpret_cast<const short8*>(&Wc[(wc * 16 + l15) * KPW + m * FP + k0 + l4 * 8]);
#pragma unroll
      for (int rt = 0; rt < 2; ++rt)
        pc[rt] = __builtin_amdgcn_mfma_f32_16x16x32_bf16(af2[rt], bfc, pc[rt], 0, 0, 0);
    }
  }

  // ---- GRU epilogue ----
  const float bcb = bc[wc * 16 + l15];
  float* hrow = reinterpret_cast<float*>(Hbuf + HB);  // buf1 fp32 overlay (proj(4) read buf0)
#pragma unroll
  for (int rt = 0; rt < 2; ++rt) {
    f32x4 hn;
    ushort4v pk;
#pragma unroll
    for (int jj = 0; jj < 4; ++jj) {
      const float ex = __expf(2.f * (pc[rt][jj] + bcb));
      const float c = 1.f - 2.f / (ex + 1.f);         // tanh
      hn[jj] = u[rt][jj] * hreg[rt][jj] + (1.f - u[rt][jj]) * c;
      pk[jj] = f2bf(hn[jj]);
    }
    hreg[rt] = hn;
    ast((u64*)(hout + (wc * 16 + l15) * 256 + n0 + r0 + rt * 16 + l4 * 4),
        __builtin_bit_cast(u64, pk));
    if (MODE == 2) {
#pragma unroll
      for (int jj = 0; jj < 4; ++jj)
        hrow[(r0 + rt * 16 + l4 * 4 + jj) * 68 + wc * 16 + l15] = hn[jj];
    }
  }
  if (MODE == 2) {
    __syncthreads();
    if (tid < 64) {
      float acc = projB[0];
      const float* hr = hrow + tid * 68;
#pragma unroll
      for (int hid = 0; hid < 64; ++hid) acc = fmaf(hr[hid], projW[hid], acc);
      outp[b * 3072 + n0 + tid] = acc;                // host-read output
      astf(xdout + b * 256 + n0 + tid, acc);          // cross-block feedback
    }
  }
}

// ---------------- persistent main kernel (256 blocks x 512) ----------------
__launch_bounds__(512, 2)
__global__ void dcrnn_main(KP p) {
  __shared__ __align__(16) unsigned short xsT[128 * 264];     // 67584 B
  __shared__ __align__(16) unsigned short Hbuf[2 * 64 * 136]; // 34816 B -> 102400, 1 blk/CU
  const int tid = threadIdx.x;
  const int i = (int)blockIdx.x;
  const int q = (i >> 3) & 3;
  const int b = (i & 7) + 8 * (i >> 5);   // batch's 4 blocks share blockIdx%8 (same XCD)
  const int n0 = q * 64;

  // one-time LDS zero (pads + stale protection for first cell)
  for (int e = tid; e < 128 * 264; e += 512) xsT[e] = 0;
  for (int e = tid; e < 2 * 64 * 136; e += 512) Hbuf[e] = 0;
  __syncthreads();

  unsigned* ctr = p.ctr + b * 64;
  unsigned st = 0;
  auto BAR = [&]() {
    ++st;
    asm volatile("s_waitcnt vmcnt(0)" ::: "memory");  // state stores visible
    __syncthreads();
    if (tid == 0) {
      __hip_atomic_fetch_add(ctr, 1u, __ATOMIC_RELAXED, __HIP_MEMORY_SCOPE_AGENT);
      const unsigned target = st * 4u;
      while (__hip_atomic_load(ctr, __ATOMIC_RELAXED, __HIP_MEMORY_SCOPE_AGENT) < target)
        __builtin_amdgcn_s_sleep(2);
    }
    __syncthreads();
  };

  f32x4 h0[2], h1[2];
#pragma unroll
  for (int rt = 0; rt < 2; ++rt) { h0[rt] = 0.f; h1[rt] = 0.f; }
  int c0 = 0, c1 = 0;

  // ---- encoder ----
  for (int t = 0; t < 12; ++t) {
    const float* x0 = p.enc_in + (b * 12 + t) * 512;
    cell_stage<2, 96, 1>(b, q, n0, tid, x0, nullptr, p.H0[c0] + b * 16384, p.A5,
                         p.Wp[0], p.bias[0], p.Wp[1], p.bias[1], h0,
                         p.H0[c0 ^ 1] + b * 16384, nullptr, nullptr, nullptr, nullptr, xsT, Hbuf);
    BAR(); c0 ^= 1;
    cell_stage<64, 128, 1>(b, q, n0, tid, nullptr, p.H0[c0] + b * 16384, p.H1[c1] + b * 16384, p.A5,
                           p.Wp[2], p.bias[2], p.Wp[3], p.bias[3], h1,
                           p.H1[c1 ^ 1] + b * 16384, nullptr, nullptr, nullptr, nullptr, xsT, Hbuf);
    BAR(); c1 ^= 1;
  }

  // ---- decoder ----
  for (int t = 0; t < 12; ++t) {
    const float* xd = t ? (p.XD + b * 256) : nullptr;
    cell_stage<1, 96, 1>(b, q, n0, tid, xd, nullptr, p.H0[c0] + b * 16384, p.A5,
                         p.Wp[4], p.bias[4], p.Wp[5], p.bias[5], h0,
                         p.H0[c0 ^ 1] + b * 16384, nullptr, nullptr, nullptr, nullptr, xsT, Hbuf);
    BAR(); c0 ^= 1;
    cell_stage<64, 128, 2>(b, q, n0, tid, nullptr, p.H0[c0] + b * 16384, p.H1[c1] + b * 16384, p.A5,
                           p.Wp[6], p.bias[6], p.Wp[7], p.bias[7], h1,
                           p.H1[c1 ^ 1] + b * 16384, p.prW, p.prB, p.out + t * 256, p.XD, xsT, Hbuf);
    if (t != 11) BAR();
    c1 ^= 1;
  }
}

// ---------------- host ----------------
extern "C" void kernel_launch(void* const* d_in, const int* in_sizes, int n_in,
                              void* d_out, int out_size, void* d_ws, size_t ws_size,
                              hipStream_t stream)
{
  (void)in_sizes; (void)n_in; (void)out_size; (void)ws_size;
  KP p;
  p.enc_in = (const float*)d_in[0];
  p.sup0 = (const float*)d_in[2];
  p.sup1 = (const float*)d_in[3];
  p.Wsrc[0] = (const float*)d_in[4];  p.bias[0] = (const float*)d_in[5];
  p.Wsrc[1] = (const float*)d_in[6];  p.bias[1] = (const float*)d_in[7];
  p.Wsrc[2] = (const float*)d_in[8];  p.bias[2] = (const float*)d_in[9];
  p.Wsrc[3] = (const float*)d_in[10]; p.bias[3] = (const float*)d_in[11];
  p.Wsrc[4] = (const float*)d_in[12]; p.bias[4] = (const float*)d_in[13];
  p.Wsrc[5] = (const float*)d_in[14]; p.bias[5] = (const float*)d_in[15];
  p.Wsrc[6] = (const float*)d_in[16]; p.bias[6] = (const float*)d_in[17];
  p.Wsrc[7] = (const float*)d_in[18]; p.bias[7] = (const float*)d_in[19];
  p.prW = (const float*)d_in[20];
  p.prB = (const float*)d_in[21];
  p.out = (float*)d_out;

  char* ws = (char*)d_ws;
  size_t off = 0;
  auto carve = [&](size_t bytes) -> char* {
    char* qp = ws + off;
    off += (bytes + 255) & ~(size_t)255;
    return qp;
  };
  p.A5 = (unsigned short*)carve(5 * 65536 * 2);
  p.Wp[0] = (unsigned short*)carve(128 * 480 * 2);
  p.Wp[1] = (unsigned short*)carve(64 * 480 * 2);
  p.Wp[2] = (unsigned short*)carve(128 * 640 * 2);
  p.Wp[3] = (unsigned short*)carve(64 * 640 * 2);
  p.Wp[4] = (unsigned short*)carve(128 * 480 * 2);
  p.Wp[5] = (unsigned short*)carve(64 * 480 * 2);
  p.Wp[6] = (unsigned short*)carve(128 * 640 * 2);
  p.Wp[7] = (unsigned short*)carve(64 * 640 * 2);
  p.H0[0] = (unsigned short*)carve(64 * 64 * 256 * 2);
  p.H0[1] = (unsigned short*)carve(64 * 64 * 256 * 2);
  p.H1[0] = (unsigned short*)carve(64 * 64 * 256 * 2);
  p.H1[1] = (unsigned short*)carve(64 * 64 * 256 * 2);
  p.XD = (float*)carve(64 * 256 * 4);
  p.ctr = (unsigned*)carve(64 * 256);

  prep<<<dim3(512), dim3(256), 0, stream>>>(p);
  dcrnn_main<<<dim3(256), dim3(512), 0, stream>>>(p);
}

// Round 16
// 2929.435 us; speedup vs baseline: 1.9641x; 1.9641x over previous
//
#include <hip/hip_runtime.h>
#include <stdint.h>

// DCRNN forward, MI355X — R16 = R13 two-stage protocol with the intra-stage
// sync chain collapsed: 10 sync'd phases/stage -> 2.
//  Measured basis (R13 vs R15): time ∝ sync'd-phase count at ~2.3us/phase;
//  work inside a phase is nearly free (MFMA ~0.3us/phase). So: give each hop
//  its own Hbuf buffer (5 x 64x136 bf16 = 87KB; +xsT 67.6KB = 154.6KB LDS),
//  identity = hop m=0 with A0=I (bf16-exact, kills the transpose phase):
//   stage xsT -> sync -> [5 hops -> Hbuf[m], no syncs] -> sync ->
//   [5 projs accumulate, no syncs] -> epilogue -> barrier.
//  - 256 blocks x 512 thr = 64 batches x 4 quadrants; 1 block/CU (LDS-forced)
//    -> co-residency; per-batch 4-block barrier (relaxed agent atomics,
//    same-XCD via blockIdx%8). State exchange: 8B agent-scope atomics.
//  - h/u in MFMA-fragment registers; XSTAGE skip for cand stages (R13-proven).
//  - FP=96 stages never read Hbuf cols >=96; FP=128 rewrites all -> MODE-2
//    fp32 overlay can't poison later stages.

typedef short short8 __attribute__((ext_vector_type(8)));
typedef float f32x4 __attribute__((ext_vector_type(4)));
typedef unsigned short ushort4v __attribute__((ext_vector_type(4)));
typedef unsigned long long u64;
typedef u64 u64x2 __attribute__((ext_vector_type(2)));

#define DEVI __device__ __forceinline__

DEVI unsigned short f2bf(float x) {
  unsigned int u = __builtin_bit_cast(unsigned int, x);
  u += 0x7FFFu + ((u >> 16) & 1u);  // RNE
  return (unsigned short)(u >> 16);
}
DEVI u64 ald(const u64* p) { return __hip_atomic_load(p, __ATOMIC_RELAXED, __HIP_MEMORY_SCOPE_AGENT); }
DEVI void ast(u64* p, u64 v) { __hip_atomic_store(p, v, __ATOMIC_RELAXED, __HIP_MEMORY_SCOPE_AGENT); }
DEVI float aldf(const float* p) { return __hip_atomic_load(p, __ATOMIC_RELAXED, __HIP_MEMORY_SCOPE_AGENT); }
DEVI void astf(float* p, float v) { __hip_atomic_store(p, v, __ATOMIC_RELAXED, __HIP_MEMORY_SCOPE_AGENT); }

struct KP {
  const float* enc_in;
  const float* sup0; const float* sup1;
  const float* Wsrc[8];
  const float* bias[8];
  const float* prW; const float* prB;
  float* out;
  unsigned short* A5;       // [5][256][256] bf16: I, S0, 2S0^2-I, S1, 2S1^2-I
  unsigned short* Wp[8];    // packed [O][5*FP] bf16 (m=0 = identity slice)
  unsigned short* H0[2];    // [64 b][64 f][256 n] bf16 rows, ping-pong
  unsigned short* H1[2];
  unsigned short* RH0;      // r*h rows
  unsigned short* RH1;
  float* XD;                // [64][256] decoder feedback
  unsigned* ctr;            // 64 per-batch counters, 256B apart
};

// ---------------- prep kernel (512 blocks x 256) ----------------
__global__ void prep(KP p) {
  const int i = blockIdx.x, tid = threadIdx.x;
  {  // A5 matrices (m0 = exact bf16 identity)
    const int s = i & 1, r = i >> 1;
    const float* S = s ? p.sup1 : p.sup0;
    float acc = 0.f;
    for (int k = 0; k < 256; ++k) acc = fmaf(S[r * 256 + k], S[k * 256 + tid], acc);
    if (s == 0) p.A5[r * 256 + tid] = (r == tid) ? (unsigned short)0x3F80 : (unsigned short)0;
    p.A5[(1 + 2 * s) * 65536 + r * 256 + tid] = f2bf(S[r * 256 + tid]);
    p.A5[(2 + 2 * s) * 65536 + r * 256 + tid] = f2bf(2.f * acc - (r == tid ? 1.f : 0.f));
  }
  {  // packed weights: Wp[o][m*FP+f] = W[f,m,o], f zero-padded to FP
    const int gtid = i * 256 + tid;
    const int Fs[8]  = {66, 66, 128, 128, 65, 65, 128, 128};
    const int Os[8]  = {128, 64, 128, 64, 128, 64, 128, 64};
    const int FPs[8] = {96, 96, 128, 128, 96, 96, 128, 128};
    for (int w = 0; w < 8; ++w) {
      const int FPw = FPs[w], KPw = 5 * FPw, tot = Os[w] * KPw;
      for (int e = gtid; e < tot; e += 512 * 256) {
        const int o = e / KPw, k2 = e - o * KPw, m = k2 / FPw, f = k2 - m * FPw;
        p.Wp[w][e] = f2bf((f < Fs[w]) ? p.Wsrc[w][(f * 5 + m) * Os[w] + o] : 0.f);
      }
    }
  }
  {  // zero initial hidden via agent-scope stores
    const int gtid = i * 256 + tid;
    u64* z0 = (u64*)p.H0[0];
    u64* z1 = (u64*)p.H1[0];
    ast(z0 + 2 * gtid, 0); ast(z0 + 2 * gtid + 1, 0);
    ast(z1 + 2 * gtid, 0); ast(z1 + 2 * gtid + 1, 0);
  }
  if (i == 0 && tid < 64)
    __hip_atomic_store(p.ctr + tid * 64, 0u, __ATOMIC_RELAXED, __HIP_MEMORY_SCOPE_AGENT);
}

// ---------------- fused diffusion-conv stage (2 sync'd phases) ----------------
// MODE 0: gates (O=128, sigmoid; writes RH rows, u regs)
// MODE 1: cand  (O=64, tanh; GRU update of hreg; writes H rows)
// MODE 2: MODE1 + final projection (writes out slice and XD)
// XSTAGE: stage x-part into xsT (gates only; persists into cand, R13-proven).
template<int IND, int FP, int MODE, bool XSTAGE>
DEVI void dc_stage(int b, int n0, int tid,
                   const float* xf32,             // IND<=2 x input (IND==1 via agent ld)
                   const unsigned short* xbf,     // IND==64 bf16 rows [64][256]
                   const unsigned short* hrows,   // bf16 rows [64][256] (h or r*h)
                   const unsigned short* A5,
                   const unsigned short* Wp, const float* bias,
                   f32x4 (&hreg)[2], f32x4 (&ureg)[2],
                   unsigned short* grows,         // output rows (RH or Hnew)
                   const float* projW, const float* projB,
                   float* outp, float* xdout,
                   unsigned short* xsT, unsigned short* Hbuf)
{
  constexpr int O = (MODE == 0) ? 128 : 64;
  constexpr int KPW = 5 * FP;
  constexpr int XS = 264;            // xsT row stride (bf16 elems)
  constexpr int HS = 136;            // Hbuf row stride
  constexpr int HB = 64 * HS;        // one Hbuf buffer (per hop)
  constexpr int NFT = FP / 16;
  constexpr int NOT_ = O / 16;
  constexpr int FT_W = (NFT + 3) / 4;
  constexpr int OT_W = (NOT_ + 3) / 4;

  const int wv8 = tid >> 6, ln = tid & 63;
  const int l15 = ln & 15, l4 = ln >> 4;
  const int wr = wv8 & 1, wc = wv8 >> 1;   // row-half / tile-column quarter
  const int r0 = wr * 32;

  // ---- stage xsT [f][n]: h-part always; x-part only when XSTAGE ----
  {
    u64 la[4], lb[4];
    const u64* src = (const u64*)hrows;
#pragma unroll
    for (int it = 0; it < 4; ++it) {
      const int g = tid + it * 512;
      la[it] = ald(src + 2 * g); lb[it] = ald(src + 2 * g + 1);
    }
#pragma unroll
    for (int it = 0; it < 4; ++it) {
      const int g = tid + it * 512, row = g >> 5, c = g & 31;
      u64x2 v; v[0] = la[it]; v[1] = lb[it];
      *reinterpret_cast<u64x2*>(&xsT[(IND + row) * XS + c * 8]) = v;
    }
  }
  if (XSTAGE) {
    if (IND == 64) {
      u64 la[4], lb[4];
      const u64* src = (const u64*)xbf;
#pragma unroll
      for (int it = 0; it < 4; ++it) {
        const int g = tid + it * 512;
        la[it] = ald(src + 2 * g); lb[it] = ald(src + 2 * g + 1);
      }
#pragma unroll
      for (int it = 0; it < 4; ++it) {
        const int g = tid + it * 512, row = g >> 5, c = g & 31;
        u64x2 v; v[0] = la[it]; v[1] = lb[it];
        *reinterpret_cast<u64x2*>(&xsT[row * XS + c * 8]) = v;
      }
    } else if (IND == 2) {
      const float v = xf32[tid];               // read-only input, cached
      xsT[(tid & 1) * XS + (tid >> 1)] = f2bf(v);
    } else {  // IND == 1 (decoder feedback)
      if (tid < 256) xsT[tid] = xf32 ? f2bf(aldf(xf32 + tid)) : (unsigned short)0;
    }
  }
  __syncthreads();   // ---- sync 1 ----

  // ---- PHASE A: all 5 hops (m=0 identity) -> Hbuf[m]; no intra-phase syncs ----
#pragma unroll
  for (int m = 0; m < 5; ++m) {
    const unsigned short* Am = A5 + m * 65536;
    f32x4 hacc[2][FT_W];
#pragma unroll
    for (int rt = 0; rt < 2; ++rt)
#pragma unroll
      for (int fi = 0; fi < FT_W; ++fi) hacc[rt][fi] = 0.f;
#pragma unroll
    for (int k0 = 0; k0 < 256; k0 += 32) {
      short8 af[2];
#pragma unroll
      for (int rt = 0; rt < 2; ++rt)
        af[rt] = *reinterpret_cast<const short8*>(&Am[(n0 + r0 + rt * 16 + l15) * 256 + k0 + l4 * 8]);
#pragma unroll
      for (int fi = 0; fi < FT_W; ++fi) {
        const int ft = wc + 4 * fi;
        if (ft < NFT) {
          short8 bf = *reinterpret_cast<const short8*>(&xsT[(ft * 16 + l15) * XS + k0 + l4 * 8]);
#pragma unroll
          for (int rt = 0; rt < 2; ++rt)
            hacc[rt][fi] = __builtin_amdgcn_mfma_f32_16x16x32_bf16(af[rt], bf, hacc[rt][fi], 0, 0, 0);
        }
      }
    }
    unsigned short* dst = Hbuf + m * HB;
#pragma unroll
    for (int fi = 0; fi < FT_W; ++fi) {
      const int ft = wc + 4 * fi;
      if (ft < NFT) {
#pragma unroll
        for (int rt = 0; rt < 2; ++rt)
#pragma unroll
          for (int j = 0; j < 4; ++j)
            dst[(r0 + rt * 16 + l4 * 4 + j) * HS + ft * 16 + l15] = f2bf(hacc[rt][fi][j]);
      }
    }
  }
  __syncthreads();   // ---- sync 2 ----

  // ---- PHASE B: all 5 projs accumulate; no syncs ----
  f32x4 pacc[2][OT_W];
#pragma unroll
  for (int rt = 0; rt < 2; ++rt)
#pragma unroll
    for (int oi = 0; oi < OT_W; ++oi) pacc[rt][oi] = 0.f;
#pragma unroll
  for (int m = 0; m < 5; ++m) {
    const unsigned short* hb = Hbuf + m * HB;
#pragma unroll
    for (int k0 = 0; k0 < FP; k0 += 32) {
      short8 af[2];
#pragma unroll
      for (int rt = 0; rt < 2; ++rt)
        af[rt] = *reinterpret_cast<const short8*>(&hb[(r0 + rt * 16 + l15) * HS + k0 + l4 * 8]);
#pragma unroll
      for (int oi = 0; oi < OT_W; ++oi) {
        const int ot = wc + 4 * oi;
        if (ot < NOT_) {
          short8 bf = *reinterpret_cast<const short8*>(&Wp[(ot * 16 + l15) * KPW + m * FP + k0 + l4 * 8]);
#pragma unroll
          for (int rt = 0; rt < 2; ++rt)
            pacc[rt][oi] = __builtin_amdgcn_mfma_f32_16x16x32_bf16(af[rt], bf, pacc[rt][oi], 0, 0, 0);
        }
      }
    }
  }

  // ---- epilogue ----
  if (MODE == 0) {
    const float br = bias[wc * 16 + l15];
    const float bu = bias[64 + wc * 16 + l15];
#pragma unroll
    for (int rt = 0; rt < 2; ++rt) {
      f32x4 uu;
      ushort4v pk;
#pragma unroll
      for (int jj = 0; jj < 4; ++jj) {
        const float r = 1.f / (1.f + __expf(-(pacc[rt][0][jj] + br)));
        uu[jj] = 1.f / (1.f + __expf(-(pacc[rt][1][jj] + bu)));
        pk[jj] = f2bf(r * hreg[rt][jj]);
      }
      ureg[rt] = uu;
      ast((u64*)(grows + (wc * 16 + l15) * 256 + n0 + r0 + rt * 16 + l4 * 4),
          __builtin_bit_cast(u64, pk));
    }
  } else {
    float* hrow = reinterpret_cast<float*>(Hbuf);   // Hbuf[0] fp32 overlay [64][68]
    if (MODE == 2) __syncthreads();                 // phase-B readers done
    const float bc = bias[wc * 16 + l15];
#pragma unroll
    for (int rt = 0; rt < 2; ++rt) {
      f32x4 hn;
      ushort4v pk;
#pragma unroll
      for (int jj = 0; jj < 4; ++jj) {
        const float ex = __expf(2.f * (pacc[rt][0][jj] + bc));
        const float c = 1.f - 2.f / (ex + 1.f);     // tanh
        hn[jj] = ureg[rt][jj] * hreg[rt][jj] + (1.f - ureg[rt][jj]) * c;
        pk[jj] = f2bf(hn[jj]);
      }
      hreg[rt] = hn;
      ast((u64*)(grows + (wc * 16 + l15) * 256 + n0 + r0 + rt * 16 + l4 * 4),
          __builtin_bit_cast(u64, pk));
      if (MODE == 2) {
#pragma unroll
        for (int jj = 0; jj < 4; ++jj)
          hrow[(r0 + rt * 16 + l4 * 4 + jj) * 68 + wc * 16 + l15] = hn[jj];
      }
    }
    if (MODE == 2) {
      __syncthreads();
      if (tid < 64) {
        float acc = projB[0];
        const float* hr = hrow + tid * 68;
#pragma unroll
        for (int hid = 0; hid < 64; ++hid) acc = fmaf(hr[hid], projW[hid], acc);
        outp[b * 3072 + n0 + tid] = acc;            // host-read output
        astf(xdout + b * 256 + n0 + tid, acc);      // cross-block feedback
      }
    }
  }
}

// ---------------- persistent main kernel (256 blocks x 512) ----------------
__launch_bounds__(512, 2)
__global__ void dcrnn_main(KP p) {
  __shared__ __align__(16) unsigned short xsT[128 * 264];     // 67584 B
  __shared__ __align__(16) unsigned short Hbuf[5 * 64 * 136]; // 87040 B -> 154624 total, 1 blk/CU
  const int tid = threadIdx.x;
  const int i = (int)blockIdx.x;
  const int q = (i >> 3) & 3;
  const int b = (i & 7) + 8 * (i >> 5);   // batch's 4 blocks share blockIdx%8 (same XCD)
  const int n0 = q * 64;

  // one-time LDS zero (pads + stale protection for first stage)
  for (int e = tid; e < 128 * 264; e += 512) xsT[e] = 0;
  for (int e = tid; e < 5 * 64 * 136; e += 512) Hbuf[e] = 0;
  __syncthreads();

  unsigned* ctr = p.ctr + b * 64;
  unsigned st = 0;
  auto BAR = [&]() {
    ++st;
    asm volatile("s_waitcnt vmcnt(0)" ::: "memory");  // state stores visible
    __syncthreads();
    if (tid == 0) {
      __hip_atomic_fetch_add(ctr, 1u, __ATOMIC_RELAXED, __HIP_MEMORY_SCOPE_AGENT);
      const unsigned target = st * 4u;
      while (__hip_atomic_load(ctr, __ATOMIC_RELAXED, __HIP_MEMORY_SCOPE_AGENT) < target)
        __builtin_amdgcn_s_sleep(2);
    }
    __syncthreads();
  };

  f32x4 h0[2], h1[2], u[2];
#pragma unroll
  for (int rt = 0; rt < 2; ++rt) { h0[rt] = 0.f; h1[rt] = 0.f; u[rt] = 0.f; }
  int c0 = 0, c1 = 0;

  // ---- encoder ----
  for (int t = 0; t < 12; ++t) {
    const float* x0 = p.enc_in + (b * 12 + t) * 512;
    dc_stage<2, 96, 0, true >(b, n0, tid, x0, nullptr, p.H0[c0] + b * 16384, p.A5, p.Wp[0], p.bias[0],
                              h0, u, p.RH0 + b * 16384, nullptr, nullptr, nullptr, nullptr, xsT, Hbuf);
    BAR();
    dc_stage<2, 96, 1, false>(b, n0, tid, x0, nullptr, p.RH0 + b * 16384, p.A5, p.Wp[1], p.bias[1],
                              h0, u, p.H0[c0 ^ 1] + b * 16384, nullptr, nullptr, nullptr, nullptr, xsT, Hbuf);
    BAR(); c0 ^= 1;
    dc_stage<64, 128, 0, true >(b, n0, tid, nullptr, p.H0[c0] + b * 16384, p.H1[c1] + b * 16384, p.A5, p.Wp[2], p.bias[2],
                                h1, u, p.RH1 + b * 16384, nullptr, nullptr, nullptr, nullptr, xsT, Hbuf);
    BAR();
    dc_stage<64, 128, 1, false>(b, n0, tid, nullptr, p.H0[c0] + b * 16384, p.RH1 + b * 16384, p.A5, p.Wp[3], p.bias[3],
                                h1, u, p.H1[c1 ^ 1] + b * 16384, nullptr, nullptr, nullptr, nullptr, xsT, Hbuf);
    BAR(); c1 ^= 1;
  }

  // ---- decoder ----
  for (int t = 0; t < 12; ++t) {
    const float* xd = t ? (p.XD + b * 256) : nullptr;
    dc_stage<1, 96, 0, true >(b, n0, tid, xd, nullptr, p.H0[c0] + b * 16384, p.A5, p.Wp[4], p.bias[4],
                              h0, u, p.RH0 + b * 16384, nullptr, nullptr, nullptr, nullptr, xsT, Hbuf);
    BAR();
    dc_stage<1, 96, 1, false>(b, n0, tid, xd, nullptr, p.RH0 + b * 16384, p.A5, p.Wp[5], p.bias[5],
                              h0, u, p.H0[c0 ^ 1] + b * 16384, nullptr, nullptr, nullptr, nullptr, xsT, Hbuf);
    BAR(); c0 ^= 1;
    dc_stage<64, 128, 0, true >(b, n0, tid, nullptr, p.H0[c0] + b * 16384, p.H1[c1] + b * 16384, p.A5, p.Wp[6], p.bias[6],
                                h1, u, p.RH1 + b * 16384, nullptr, nullptr, nullptr, nullptr, xsT, Hbuf);
    BAR();
    dc_stage<64, 128, 2, false>(b, n0, tid, nullptr, p.H0[c0] + b * 16384, p.RH1 + b * 16384, p.A5, p.Wp[7], p.bias[7],
                                h1, u, p.H1[c1 ^ 1] + b * 16384, p.prW, p.prB, p.out + t * 256, p.XD, xsT, Hbuf);
    if (t != 11) BAR();
    c1 ^= 1;
  }
}

// ---------------- host ----------------
extern "C" void kernel_launch(void* const* d_in, const int* in_sizes, int n_in,
                              void* d_out, int out_size, void* d_ws, size_t ws_size,
                              hipStream_t stream)
{
  (void)in_sizes; (void)n_in; (void)out_size; (void)ws_size;
  KP p;
  p.enc_in = (const float*)d_in[0];
  p.sup0 = (const float*)d_in[2];
  p.sup1 = (const float*)d_in[3];
  p.Wsrc[0] = (const float*)d_in[4];  p.bias[0] = (const float*)d_in[5];
  p.Wsrc[1] = (const float*)d_in[6];  p.bias[1] = (const float*)d_in[7];
  p.Wsrc[2] = (const float*)d_in[8];  p.bias[2] = (const float*)d_in[9];
  p.Wsrc[3] = (const float*)d_in[10]; p.bias[3] = (const float*)d_in[11];
  p.Wsrc[4] = (const float*)d_in[12]; p.bias[4] = (const float*)d_in[13];
  p.Wsrc[5] = (const float*)d_in[14]; p.bias[5] = (const float*)d_in[15];
  p.Wsrc[6] = (const float*)d_in[16]; p.bias[6] = (const float*)d_in[17];
  p.Wsrc[7] = (const float*)d_in[18]; p.bias[7] = (const float*)d_in[19];
  p.prW = (const float*)d_in[20];
  p.prB = (const float*)d_in[21];
  p.out = (float*)d_out;

  char* ws = (char*)d_ws;
  size_t off = 0;
  auto carve = [&](size_t bytes) -> char* {
    char* qp = ws + off;
    off += (bytes + 255) & ~(size_t)255;
    return qp;
  };
  p.A5 = (unsigned short*)carve(5 * 65536 * 2);
  p.Wp[0] = (unsigned short*)carve(128 * 480 * 2);
  p.Wp[1] = (unsigned short*)carve(64 * 480 * 2);
  p.Wp[2] = (unsigned short*)carve(128 * 640 * 2);
  p.Wp[3] = (unsigned short*)carve(64 * 640 * 2);
  p.Wp[4] = (unsigned short*)carve(128 * 480 * 2);
  p.Wp[5] = (unsigned short*)carve(64 * 480 * 2);
  p.Wp[6] = (unsigned short*)carve(128 * 640 * 2);
  p.Wp[7] = (unsigned short*)carve(64 * 640 * 2);
  p.H0[0] = (unsigned short*)carve(64 * 64 * 256 * 2);
  p.H0[1] = (unsigned short*)carve(64 * 64 * 256 * 2);
  p.H1[0] = (unsigned short*)carve(64 * 64 * 256 * 2);
  p.H1[1] = (unsigned short*)carve(64 * 64 * 256 * 2);
  p.RH0 = (unsigned short*)carve(64 * 64 * 256 * 2);
  p.RH1 = (unsigned short*)carve(64 * 64 * 256 * 2);
  p.XD = (float*)carve(64 * 256 * 4);
  p.ctr = (unsigned*)carve(64 * 256);

  prep<<<dim3(512), dim3(256), 0, stream>>>(p);
  dcrnn_main<<<dim3(256), dim3(512), 0, stream>>>(p);
}

// Round 17
// 2726.990 us; speedup vs baseline: 2.1099x; 1.0742x over previous
//
#include <hip/hip_runtime.h>
#include <stdint.h>

// DCRNN forward, MI355X — R17 = R13 (best: 2278us, FETCH 106MB) with dead
// syncs removed WITHOUT changing the A/Wp memory-access order (R16 showed
// phase restructuring collapses L2 hit rate: FETCH 106->396MB).
//  (1) identity-transpose fused into staging (same bf16 bits, -1 phase/sync;
//      cand stages rebuild only the x-part of Hbuf identity from xsT);
//  (2) Hbuf double-buffered: {hop(m) || proj(m-1)} -> write other buf -> sync
//      (hop m / proj m stay temporally adjacent -> same per-XCD L2 locality).
//  Syncs/stage ~12 -> ~7. Everything else byte-equal to R13: 256x512, 64
//  batches x 4 quadrants, per-batch 4-block barrier (relaxed agent atomics,
//  same-XCD), 8B agent-scope state exchange, XSTAGE skip, one-time pad zero.

typedef short short8 __attribute__((ext_vector_type(8)));
typedef float f32x4 __attribute__((ext_vector_type(4)));
typedef unsigned short ushort4v __attribute__((ext_vector_type(4)));
typedef unsigned long long u64;
typedef u64 u64x2 __attribute__((ext_vector_type(2)));

#define DEVI __device__ __forceinline__

DEVI unsigned short f2bf(float x) {
  unsigned int u = __builtin_bit_cast(unsigned int, x);
  u += 0x7FFFu + ((u >> 16) & 1u);  // RNE
  return (unsigned short)(u >> 16);
}
DEVI u64 ald(const u64* p) { return __hip_atomic_load(p, __ATOMIC_RELAXED, __HIP_MEMORY_SCOPE_AGENT); }
DEVI void ast(u64* p, u64 v) { __hip_atomic_store(p, v, __ATOMIC_RELAXED, __HIP_MEMORY_SCOPE_AGENT); }
DEVI float aldf(const float* p) { return __hip_atomic_load(p, __ATOMIC_RELAXED, __HIP_MEMORY_SCOPE_AGENT); }
DEVI void astf(float* p, float v) { __hip_atomic_store(p, v, __ATOMIC_RELAXED, __HIP_MEMORY_SCOPE_AGENT); }

struct KP {
  const float* enc_in;
  const float* sup0; const float* sup1;
  const float* Wsrc[8];
  const float* bias[8];
  const float* prW; const float* prB;
  float* out;
  unsigned short* A;        // [4][256][256] bf16
  unsigned short* Wp[8];    // packed [O][5*FP] bf16
  unsigned short* H0[2];    // [64 b][64 f][256 n] bf16 rows, ping-pong
  unsigned short* H1[2];
  unsigned short* RH0;      // r*h rows
  unsigned short* RH1;
  float* XD;                // [64][256] decoder feedback
  unsigned* ctr;            // 64 per-batch counters, 256B apart
};

// ---------------- prep kernel (512 blocks x 256) ----------------
__global__ void prep(KP p) {
  const int i = blockIdx.x, tid = threadIdx.x;
  {  // A matrices
    const int s = i & 1, r = i >> 1;
    const float* S = s ? p.sup1 : p.sup0;
    float acc = 0.f;
    for (int k = 0; k < 256; ++k) acc = fmaf(S[r * 256 + k], S[k * 256 + tid], acc);
    p.A[(2 * s + 0) * 65536 + r * 256 + tid] = f2bf(S[r * 256 + tid]);
    p.A[(2 * s + 1) * 65536 + r * 256 + tid] = f2bf(2.f * acc - (r == tid ? 1.f : 0.f));
  }
  {  // packed weights: Wp[o][m*FP+f] = W[f,m,o], f zero-padded to FP
    const int gtid = i * 256 + tid;
    const int Fs[8]  = {66, 66, 128, 128, 65, 65, 128, 128};
    const int Os[8]  = {128, 64, 128, 64, 128, 64, 128, 64};
    const int FPs[8] = {96, 96, 128, 128, 96, 96, 128, 128};
    for (int w = 0; w < 8; ++w) {
      const int FPw = FPs[w], KPw = 5 * FPw, tot = Os[w] * KPw;
      for (int e = gtid; e < tot; e += 512 * 256) {
        const int o = e / KPw, k2 = e - o * KPw, m = k2 / FPw, f = k2 - m * FPw;
        p.Wp[w][e] = f2bf((f < Fs[w]) ? p.Wsrc[w][(f * 5 + m) * Os[w] + o] : 0.f);
      }
    }
  }
  {  // zero initial hidden via agent-scope stores
    const int gtid = i * 256 + tid;
    u64* z0 = (u64*)p.H0[0];
    u64* z1 = (u64*)p.H1[0];
    ast(z0 + 2 * gtid, 0); ast(z0 + 2 * gtid + 1, 0);
    ast(z1 + 2 * gtid, 0); ast(z1 + 2 * gtid + 1, 0);
  }
  if (i == 0 && tid < 64)
    __hip_atomic_store(p.ctr + tid * 64, 0u, __ATOMIC_RELAXED, __HIP_MEMORY_SCOPE_AGENT);
}

// ---------------- fused diffusion-conv stage (R13 order, fewer syncs) ----------------
// MODE 0: gates (O=128, sigmoid; writes RH rows, u regs)
// MODE 1: cand  (O=64, tanh; GRU update of hreg; writes H rows)
// MODE 2: MODE1 + final projection (writes out slice and XD)
// XSTAGE: stage x-part into xsT (gates only; persists into cand, R13-proven).
template<int IND, int FP, int MODE, bool XSTAGE>
DEVI void dc_stage(int b, int n0, int tid,
                   const float* xf32,             // IND<=2 x input (IND==1 via agent ld)
                   const unsigned short* xbf,     // IND==64 bf16 rows [64][256]
                   const unsigned short* hrows,   // bf16 rows [64][256] (h or r*h)
                   const unsigned short* Amats,
                   const unsigned short* Wp, const float* bias,
                   f32x4 (&hreg)[2], f32x4 (&ureg)[2],
                   unsigned short* grows,         // output rows (RH or Hnew)
                   const float* projW, const float* projB,
                   float* outp, float* xdout,
                   unsigned short* xsT, unsigned short* Hbuf)
{
  constexpr int O = (MODE == 0) ? 128 : 64;
  constexpr int KPW = 5 * FP;
  constexpr int XS = 264;            // xsT row stride (bf16 elems)
  constexpr int HS = 136;            // Hbuf row stride
  constexpr int HB = 64 * HS;        // one Hbuf buffer
  constexpr int NFT = FP / 16;
  constexpr int NOT_ = O / 16;
  constexpr int FT_W = (NFT + 3) / 4;
  constexpr int OT_W = (NOT_ + 3) / 4;

  const int wv8 = tid >> 6, ln = tid & 63;
  const int l15 = ln & 15, l4 = ln >> 4;
  const int wr = wv8 & 1, wc = wv8 >> 1;   // row-half / tile-column quarter
  const int r0 = wr * 32;

  // ---- stage xsT [f][n] + fused Hbuf(buf0) identity writes ----
  {
    u64 la[4], lb[4];
    const u64* src = (const u64*)hrows;
#pragma unroll
    for (int it = 0; it < 4; ++it) {
      const int g = tid + it * 512;
      la[it] = ald(src + 2 * g); lb[it] = ald(src + 2 * g + 1);
    }
#pragma unroll
    for (int it = 0; it < 4; ++it) {
      const int g = tid + it * 512, row = g >> 5, c = g & 31;
      u64x2 v; v[0] = la[it]; v[1] = lb[it];
      *reinterpret_cast<u64x2*>(&xsT[(IND + row) * XS + c * 8]) = v;
      const int c8 = c * 8;
      if ((unsigned)(c8 - n0) < 64u) {   // chunk fully inside [n0, n0+64)
        const int nl = c8 - n0;
#pragma unroll
        for (int j = 0; j < 4; ++j) {
          Hbuf[(nl + j) * HS + IND + row]     = (unsigned short)(la[it] >> (16 * j));
          Hbuf[(nl + 4 + j) * HS + IND + row] = (unsigned short)(lb[it] >> (16 * j));
        }
      }
    }
  }
  if (XSTAGE) {
    if (IND == 64) {
      u64 la[4], lb[4];
      const u64* src = (const u64*)xbf;
#pragma unroll
      for (int it = 0; it < 4; ++it) {
        const int g = tid + it * 512;
        la[it] = ald(src + 2 * g); lb[it] = ald(src + 2 * g + 1);
      }
#pragma unroll
      for (int it = 0; it < 4; ++it) {
        const int g = tid + it * 512, row = g >> 5, c = g & 31;
        u64x2 v; v[0] = la[it]; v[1] = lb[it];
        *reinterpret_cast<u64x2*>(&xsT[row * XS + c * 8]) = v;
        const int c8 = c * 8;
        if ((unsigned)(c8 - n0) < 64u) {
          const int nl = c8 - n0;
#pragma unroll
          for (int j = 0; j < 4; ++j) {
            Hbuf[(nl + j) * HS + row]     = (unsigned short)(la[it] >> (16 * j));
            Hbuf[(nl + 4 + j) * HS + row] = (unsigned short)(lb[it] >> (16 * j));
          }
        }
      }
    } else if (IND == 2) {
      const float v = xf32[tid];               // read-only input, cached
      const unsigned short s = f2bf(v);
      const int n = tid >> 1, f = tid & 1;
      xsT[f * XS + n] = s;
      if ((unsigned)(n - n0) < 64u) Hbuf[(n - n0) * HS + f] = s;
    } else {  // IND == 1 (decoder feedback)
      if (tid < 256) {
        const unsigned short s = xf32 ? f2bf(aldf(xf32 + tid)) : (unsigned short)0;
        xsT[tid] = s;
        if ((unsigned)(tid - n0) < 64u) Hbuf[(tid - n0) * HS] = s;
      }
    }
  } else {
    // cand: x-part of identity rebuilt from xsT (x rows persist since gates)
    if (IND == 64) {
      for (int e = tid; e < 64 * 64; e += 512) {
        const int f = e >> 6, nl = e & 63;
        Hbuf[nl * HS + f] = xsT[f * XS + n0 + nl];
      }
    } else if (IND == 2) {
      if (tid < 128) Hbuf[(tid >> 1) * HS + (tid & 1)] = xsT[(tid & 1) * XS + n0 + (tid >> 1)];
    } else {
      if (tid < 64) Hbuf[tid * HS] = xsT[n0 + tid];
    }
  }
  __syncthreads();   // sync 1: xsT + buf0 identity ready

  f32x4 pacc[2][OT_W];
#pragma unroll
  for (int rt = 0; rt < 2; ++rt)
#pragma unroll
    for (int oi = 0; oi < OT_W; ++oi) pacc[rt][oi] = 0.f;

  auto proj_step = [&](int m, const unsigned short* hb) {
#pragma unroll
    for (int k0 = 0; k0 < FP; k0 += 32) {
      short8 af[2];
#pragma unroll
      for (int rt = 0; rt < 2; ++rt)
        af[rt] = *reinterpret_cast<const short8*>(&hb[(r0 + rt * 16 + l15) * HS + k0 + l4 * 8]);
#pragma unroll
      for (int oi = 0; oi < OT_W; ++oi) {
        const int ot = wc + 4 * oi;
        if (ot < NOT_) {
          short8 bf = *reinterpret_cast<const short8*>(&Wp[(ot * 16 + l15) * KPW + m * FP + k0 + l4 * 8]);
#pragma unroll
          for (int rt = 0; rt < 2; ++rt)
            pacc[rt][oi] = __builtin_amdgcn_mfma_f32_16x16x32_bf16(af[rt], bf, pacc[rt][oi], 0, 0, 0);
        }
      }
    }
  };

  // ---- hop/proj interleave, double-buffered: {hop(mi) || proj(mi)} -> sync ----
  // hop mi (A index mi) writes buf[(mi+1)&1]; proj mi reads buf[mi&1].
  for (int mi = 0; mi < 4; ++mi) {
    const unsigned short* Am = Amats + mi * 65536;
    f32x4 hacc[2][FT_W];
#pragma unroll
    for (int rt = 0; rt < 2; ++rt)
#pragma unroll
      for (int fi = 0; fi < FT_W; ++fi) hacc[rt][fi] = 0.f;

#pragma unroll
    for (int k0 = 0; k0 < 256; k0 += 32) {
      short8 af[2];
#pragma unroll
      for (int rt = 0; rt < 2; ++rt)
        af[rt] = *reinterpret_cast<const short8*>(&Am[(n0 + r0 + rt * 16 + l15) * 256 + k0 + l4 * 8]);
#pragma unroll
      for (int fi = 0; fi < FT_W; ++fi) {
        const int ft = wc + 4 * fi;
        if (ft < NFT) {
          short8 bf = *reinterpret_cast<const short8*>(&xsT[(ft * 16 + l15) * XS + k0 + l4 * 8]);
#pragma unroll
          for (int rt = 0; rt < 2; ++rt)
            hacc[rt][fi] = __builtin_amdgcn_mfma_f32_16x16x32_bf16(af[rt], bf, hacc[rt][fi], 0, 0, 0);
        }
      }
    }
    proj_step(mi, Hbuf + (mi & 1) * HB);            // reads the OTHER buffer
    unsigned short* dst = Hbuf + ((mi + 1) & 1) * HB;
#pragma unroll
    for (int fi = 0; fi < FT_W; ++fi) {
      const int ft = wc + 4 * fi;
      if (ft < NFT) {
#pragma unroll
        for (int rt = 0; rt < 2; ++rt)
#pragma unroll
          for (int j = 0; j < 4; ++j)
            dst[(r0 + rt * 16 + l4 * 4 + j) * HS + ft * 16 + l15] = f2bf(hacc[rt][fi][j]);
      }
    }
    __syncthreads();
  }
  proj_step(4, Hbuf);                               // hop4's output is in buf0

  // ---- epilogue ----
  if (MODE == 0) {
    const float br = bias[wc * 16 + l15];
    const float bu = bias[64 + wc * 16 + l15];
#pragma unroll
    for (int rt = 0; rt < 2; ++rt) {
      f32x4 uu;
      ushort4v pk;
#pragma unroll
      for (int jj = 0; jj < 4; ++jj) {
        const float r = 1.f / (1.f + __expf(-(pacc[rt][0][jj] + br)));
        uu[jj] = 1.f / (1.f + __expf(-(pacc[rt][1][jj] + bu)));
        pk[jj] = f2bf(r * hreg[rt][jj]);
      }
      ureg[rt] = uu;
      ast((u64*)(grows + (wc * 16 + l15) * 256 + n0 + r0 + rt * 16 + l4 * 4),
          __builtin_bit_cast(u64, pk));
    }
  } else {
    float* hrow = reinterpret_cast<float*>(Hbuf + HB);  // buf1 overlay (proj4 reads buf0;
                                                        // buf1 fully rewritten by hop0 next stage)
    const float bc = bias[wc * 16 + l15];
#pragma unroll
    for (int rt = 0; rt < 2; ++rt) {
      f32x4 hn;
      ushort4v pk;
#pragma unroll
      for (int jj = 0; jj < 4; ++jj) {
        const float ex = __expf(2.f * (pacc[rt][0][jj] + bc));
        const float c = 1.f - 2.f / (ex + 1.f);     // tanh
        hn[jj] = ureg[rt][jj] * hreg[rt][jj] + (1.f - ureg[rt][jj]) * c;
        pk[jj] = f2bf(hn[jj]);
      }
      hreg[rt] = hn;
      ast((u64*)(grows + (wc * 16 + l15) * 256 + n0 + r0 + rt * 16 + l4 * 4),
          __builtin_bit_cast(u64, pk));
      if (MODE == 2) {
#pragma unroll
        for (int jj = 0; jj < 4; ++jj)
          hrow[(r0 + rt * 16 + l4 * 4 + jj) * 68 + wc * 16 + l15] = hn[jj];
      }
    }
    if (MODE == 2) {
      __syncthreads();
      if (tid < 64) {
        float acc = projB[0];
        const float* hr = hrow + tid * 68;
#pragma unroll
        for (int hid = 0; hid < 64; ++hid) acc = fmaf(hr[hid], projW[hid], acc);
        outp[b * 3072 + n0 + tid] = acc;            // host-read output
        astf(xdout + b * 256 + n0 + tid, acc);      // cross-block feedback
      }
    }
  }
}

// ---------------- persistent main kernel (256 blocks x 512) ----------------
__launch_bounds__(512, 2)
__global__ void dcrnn_main(KP p) {
  __shared__ __align__(16) unsigned short xsT[128 * 264];     // 67584 B
  __shared__ __align__(16) unsigned short Hbuf[2 * 64 * 136]; // 34816 B -> 102400, 1 blk/CU
  const int tid = threadIdx.x;
  const int i = (int)blockIdx.x;
  const int q = (i >> 3) & 3;
  const int b = (i & 7) + 8 * (i >> 5);   // batch's 4 blocks share blockIdx%8 (same XCD)
  const int n0 = q * 64;

  // one-time LDS zero (pads + stale protection for first stage)
  for (int e = tid; e < 128 * 264; e += 512) xsT[e] = 0;
  for (int e = tid; e < 2 * 64 * 136; e += 512) Hbuf[e] = 0;
  __syncthreads();

  unsigned* ctr = p.ctr + b * 64;
  unsigned st = 0;
  auto BAR = [&]() {
    ++st;
    asm volatile("s_waitcnt vmcnt(0)" ::: "memory");  // state stores visible
    __syncthreads();
    if (tid == 0) {
      __hip_atomic_fetch_add(ctr, 1u, __ATOMIC_RELAXED, __HIP_MEMORY_SCOPE_AGENT);
      const unsigned target = st * 4u;
      while (__hip_atomic_load(ctr, __ATOMIC_RELAXED, __HIP_MEMORY_SCOPE_AGENT) < target)
        __builtin_amdgcn_s_sleep(2);
    }
    __syncthreads();
  };

  f32x4 h0[2], h1[2], u[2];
#pragma unroll
  for (int rt = 0; rt < 2; ++rt) { h0[rt] = 0.f; h1[rt] = 0.f; u[rt] = 0.f; }
  int c0 = 0, c1 = 0;

  // ---- encoder ----
  for (int t = 0; t < 12; ++t) {
    const float* x0 = p.enc_in + (b * 12 + t) * 512;
    dc_stage<2, 96, 0, true >(b, n0, tid, x0, nullptr, p.H0[c0] + b * 16384, p.A, p.Wp[0], p.bias[0],
                              h0, u, p.RH0 + b * 16384, nullptr, nullptr, nullptr, nullptr, xsT, Hbuf);
    BAR();
    dc_stage<2, 96, 1, false>(b, n0, tid, x0, nullptr, p.RH0 + b * 16384, p.A, p.Wp[1], p.bias[1],
                              h0, u, p.H0[c0 ^ 1] + b * 16384, nullptr, nullptr, nullptr, nullptr, xsT, Hbuf);
    BAR(); c0 ^= 1;
    dc_stage<64, 128, 0, true >(b, n0, tid, nullptr, p.H0[c0] + b * 16384, p.H1[c1] + b * 16384, p.A, p.Wp[2], p.bias[2],
                                h1, u, p.RH1 + b * 16384, nullptr, nullptr, nullptr, nullptr, xsT, Hbuf);
    BAR();
    dc_stage<64, 128, 1, false>(b, n0, tid, nullptr, p.H0[c0] + b * 16384, p.RH1 + b * 16384, p.A, p.Wp[3], p.bias[3],
                                h1, u, p.H1[c1 ^ 1] + b * 16384, nullptr, nullptr, nullptr, nullptr, xsT, Hbuf);
    BAR(); c1 ^= 1;
  }

  // ---- decoder ----
  for (int t = 0; t < 12; ++t) {
    const float* xd = t ? (p.XD + b * 256) : nullptr;
    dc_stage<1, 96, 0, true >(b, n0, tid, xd, nullptr, p.H0[c0] + b * 16384, p.A, p.Wp[4], p.bias[4],
                              h0, u, p.RH0 + b * 16384, nullptr, nullptr, nullptr, nullptr, xsT, Hbuf);
    BAR();
    dc_stage<1, 96, 1, false>(b, n0, tid, xd, nullptr, p.RH0 + b * 16384, p.A, p.Wp[5], p.bias[5],
                              h0, u, p.H0[c0 ^ 1] + b * 16384, nullptr, nullptr, nullptr, nullptr, xsT, Hbuf);
    BAR(); c0 ^= 1;
    dc_stage<64, 128, 0, true >(b, n0, tid, nullptr, p.H0[c0] + b * 16384, p.H1[c1] + b * 16384, p.A, p.Wp[6], p.bias[6],
                                h1, u, p.RH1 + b * 16384, nullptr, nullptr, nullptr, nullptr, xsT, Hbuf);
    BAR();
    dc_stage<64, 128, 2, false>(b, n0, tid, nullptr, p.H0[c0] + b * 16384, p.RH1 + b * 16384, p.A, p.Wp[7], p.bias[7],
                                h1, u, p.H1[c1 ^ 1] + b * 16384, p.prW, p.prB, p.out + t * 256, p.XD, xsT, Hbuf);
    if (t != 11) BAR();
    c1 ^= 1;
  }
}

// ---------------- host ----------------
extern "C" void kernel_launch(void* const* d_in, const int* in_sizes, int n_in,
                              void* d_out, int out_size, void* d_ws, size_t ws_size,
                              hipStream_t stream)
{
  (void)in_sizes; (void)n_in; (void)out_size; (void)ws_size;
  KP p;
  p.enc_in = (const float*)d_in[0];
  p.sup0 = (const float*)d_in[2];
  p.sup1 = (const float*)d_in[3];
  p.Wsrc[0] = (const float*)d_in[4];  p.bias[0] = (const float*)d_in[5];
  p.Wsrc[1] = (const float*)d_in[6];  p.bias[1] = (const float*)d_in[7];
  p.Wsrc[2] = (const float*)d_in[8];  p.bias[2] = (const float*)d_in[9];
  p.Wsrc[3] = (const float*)d_in[10]; p.bias[3] = (const float*)d_in[11];
  p.Wsrc[4] = (const float*)d_in[12]; p.bias[4] = (const float*)d_in[13];
  p.Wsrc[5] = (const float*)d_in[14]; p.bias[5] = (const float*)d_in[15];
  p.Wsrc[6] = (const float*)d_in[16]; p.bias[6] = (const float*)d_in[17];
  p.Wsrc[7] = (const float*)d_in[18]; p.bias[7] = (const float*)d_in[19];
  p.prW = (const float*)d_in[20];
  p.prB = (const float*)d_in[21];
  p.out = (float*)d_out;

  char* ws = (char*)d_ws;
  size_t off = 0;
  auto carve = [&](size_t bytes) -> char* {
    char* qp = ws + off;
    off += (bytes + 255) & ~(size_t)255;
    return qp;
  };
  p.A = (unsigned short*)carve(4 * 65536 * 2);
  p.Wp[0] = (unsigned short*)carve(128 * 480 * 2);
  p.Wp[1] = (unsigned short*)carve(64 * 480 * 2);
  p.Wp[2] = (unsigned short*)carve(128 * 640 * 2);
  p.Wp[3] = (unsigned short*)carve(64 * 640 * 2);
  p.Wp[4] = (unsigned short*)carve(128 * 480 * 2);
  p.Wp[5] = (unsigned short*)carve(64 * 480 * 2);
  p.Wp[6] = (unsigned short*)carve(128 * 640 * 2);
  p.Wp[7] = (unsigned short*)carve(64 * 640 * 2);
  p.H0[0] = (unsigned short*)carve(64 * 64 * 256 * 2);
  p.H0[1] = (unsigned short*)carve(64 * 64 * 256 * 2);
  p.H1[0] = (unsigned short*)carve(64 * 64 * 256 * 2);
  p.H1[1] = (unsigned short*)carve(64 * 64 * 256 * 2);
  p.RH0 = (unsigned short*)carve(64 * 64 * 256 * 2);
  p.RH1 = (unsigned short*)carve(64 * 64 * 256 * 2);
  p.XD = (float*)carve(64 * 256 * 4);
  p.ctr = (unsigned*)carve(64 * 256);

  prep<<<dim3(512), dim3(256), 0, stream>>>(p);
  dcrnn_main<<<dim3(256), dim3(512), 0, stream>>>(p);
}

// Round 18
// 2635.225 us; speedup vs baseline: 2.1834x; 1.0348x over previous
//
#include <hip/hip_runtime.h>
#include <stdint.h>

// DCRNN forward, MI355X — R18 = R13 (best: 2278us, FETCH 106MB) + ONE change:
// Hbuf double-buffer (syncs/stage 10 -> 7). Single-variable test: R17 bundled
// this with fused staging and regressed (FETCH 458MB); this round isolates
// which change caused it. Staging + transpose phases byte-equal to R13.
//  Loop: {hop(mi) || proj(mi) from buf[mi&1]} -> write buf[(mi+1)&1] -> sync;
//  proj(4) from buf0. buf1 fully rewritten by hop0 each stage -> MODE-2 fp32
//  overlay (buf1) cannot poison later stages.
//  Everything else = R13: 256x512, 64 batches x 4 quadrants, per-batch 4-block
//  barrier (relaxed agent atomics, same-XCD via blockIdx%8), 8B agent-scope
//  state exchange, XSTAGE skip for cand, one-time pad zero.

typedef short short8 __attribute__((ext_vector_type(8)));
typedef float f32x4 __attribute__((ext_vector_type(4)));
typedef unsigned short ushort4v __attribute__((ext_vector_type(4)));
typedef unsigned long long u64;
typedef u64 u64x2 __attribute__((ext_vector_type(2)));

#define DEVI __device__ __forceinline__

DEVI unsigned short f2bf(float x) {
  unsigned int u = __builtin_bit_cast(unsigned int, x);
  u += 0x7FFFu + ((u >> 16) & 1u);  // RNE
  return (unsigned short)(u >> 16);
}
DEVI u64 ald(const u64* p) { return __hip_atomic_load(p, __ATOMIC_RELAXED, __HIP_MEMORY_SCOPE_AGENT); }
DEVI void ast(u64* p, u64 v) { __hip_atomic_store(p, v, __ATOMIC_RELAXED, __HIP_MEMORY_SCOPE_AGENT); }
DEVI float aldf(const float* p) { return __hip_atomic_load(p, __ATOMIC_RELAXED, __HIP_MEMORY_SCOPE_AGENT); }
DEVI void astf(float* p, float v) { __hip_atomic_store(p, v, __ATOMIC_RELAXED, __HIP_MEMORY_SCOPE_AGENT); }

struct KP {
  const float* enc_in;
  const float* sup0; const float* sup1;
  const float* Wsrc[8];
  const float* bias[8];
  const float* prW; const float* prB;
  float* out;
  unsigned short* A;        // [4][256][256] bf16
  unsigned short* Wp[8];    // packed [O][5*FP] bf16
  unsigned short* H0[2];    // [64 b][64 f][256 n] bf16 rows, ping-pong
  unsigned short* H1[2];
  unsigned short* RH0;      // r*h rows
  unsigned short* RH1;
  float* XD;                // [64][256] decoder feedback
  unsigned* ctr;            // 64 per-batch counters, 256B apart
};

// ---------------- prep kernel (512 blocks x 256) ----------------
__global__ void prep(KP p) {
  const int i = blockIdx.x, tid = threadIdx.x;
  {  // A matrices
    const int s = i & 1, r = i >> 1;
    const float* S = s ? p.sup1 : p.sup0;
    float acc = 0.f;
    for (int k = 0; k < 256; ++k) acc = fmaf(S[r * 256 + k], S[k * 256 + tid], acc);
    p.A[(2 * s + 0) * 65536 + r * 256 + tid] = f2bf(S[r * 256 + tid]);
    p.A[(2 * s + 1) * 65536 + r * 256 + tid] = f2bf(2.f * acc - (r == tid ? 1.f : 0.f));
  }
  {  // packed weights: Wp[o][m*FP+f] = W[f,m,o], f zero-padded to FP
    const int gtid = i * 256 + tid;
    const int Fs[8]  = {66, 66, 128, 128, 65, 65, 128, 128};
    const int Os[8]  = {128, 64, 128, 64, 128, 64, 128, 64};
    const int FPs[8] = {96, 96, 128, 128, 96, 96, 128, 128};
    for (int w = 0; w < 8; ++w) {
      const int FPw = FPs[w], KPw = 5 * FPw, tot = Os[w] * KPw;
      for (int e = gtid; e < tot; e += 512 * 256) {
        const int o = e / KPw, k2 = e - o * KPw, m = k2 / FPw, f = k2 - m * FPw;
        p.Wp[w][e] = f2bf((f < Fs[w]) ? p.Wsrc[w][(f * 5 + m) * Os[w] + o] : 0.f);
      }
    }
  }
  {  // zero initial hidden via agent-scope stores
    const int gtid = i * 256 + tid;
    u64* z0 = (u64*)p.H0[0];
    u64* z1 = (u64*)p.H1[0];
    ast(z0 + 2 * gtid, 0); ast(z0 + 2 * gtid + 1, 0);
    ast(z1 + 2 * gtid, 0); ast(z1 + 2 * gtid + 1, 0);
  }
  if (i == 0 && tid < 64)
    __hip_atomic_store(p.ctr + tid * 64, 0u, __ATOMIC_RELAXED, __HIP_MEMORY_SCOPE_AGENT);
}

// ---------------- fused diffusion-conv stage (R13 + Hbuf dbuf) ----------------
// MODE 0: gates (O=128, sigmoid; writes RH rows, u regs)
// MODE 1: cand  (O=64, tanh; GRU update of hreg; writes H rows)
// MODE 2: MODE1 + final projection (writes out slice and XD)
// XSTAGE: stage x-part into xsT (gates only; persists into cand, R13-proven).
template<int IND, int FP, int MODE, bool XSTAGE>
DEVI void dc_stage(int b, int n0, int tid,
                   const float* xf32,             // IND<=2 x input (IND==1 via agent ld)
                   const unsigned short* xbf,     // IND==64 bf16 rows [64][256]
                   const unsigned short* hrows,   // bf16 rows [64][256] (h or r*h)
                   const unsigned short* Amats,
                   const unsigned short* Wp, const float* bias,
                   f32x4 (&hreg)[2], f32x4 (&ureg)[2],
                   unsigned short* grows,         // output rows (RH or Hnew)
                   const float* projW, const float* projB,
                   float* outp, float* xdout,
                   unsigned short* xsT, unsigned short* Hbuf)
{
  constexpr int O = (MODE == 0) ? 128 : 64;
  constexpr int KPW = 5 * FP;
  constexpr int XS = 264;            // xsT row stride (bf16 elems)
  constexpr int HS = 136;            // Hbuf row stride
  constexpr int HB = 64 * HS;        // one Hbuf buffer
  constexpr int NFT = FP / 16;
  constexpr int NOT_ = O / 16;
  constexpr int FT_W = (NFT + 3) / 4;
  constexpr int OT_W = (NOT_ + 3) / 4;

  const int wv8 = tid >> 6, ln = tid & 63;
  const int l15 = ln & 15, l4 = ln >> 4;
  const int wr = wv8 & 1, wc = wv8 >> 1;   // row-half / tile-column quarter
  const int r0 = wr * 32;

  // ---- stage xsT [f][n]: h-part always; x-part only when XSTAGE (R13 code) ----
  {
    u64 la[4], lb[4];
    const u64* src = (const u64*)hrows;
#pragma unroll
    for (int it = 0; it < 4; ++it) {
      const int g = tid + it * 512;
      la[it] = ald(src + 2 * g); lb[it] = ald(src + 2 * g + 1);
    }
#pragma unroll
    for (int it = 0; it < 4; ++it) {
      const int g = tid + it * 512, row = g >> 5, c = g & 31;
      u64x2 v; v[0] = la[it]; v[1] = lb[it];
      *reinterpret_cast<u64x2*>(&xsT[(IND + row) * XS + c * 8]) = v;
    }
  }
  if (XSTAGE) {
    if (IND == 64) {
      u64 la[4], lb[4];
      const u64* src = (const u64*)xbf;
#pragma unroll
      for (int it = 0; it < 4; ++it) {
        const int g = tid + it * 512;
        la[it] = ald(src + 2 * g); lb[it] = ald(src + 2 * g + 1);
      }
#pragma unroll
      for (int it = 0; it < 4; ++it) {
        const int g = tid + it * 512, row = g >> 5, c = g & 31;
        u64x2 v; v[0] = la[it]; v[1] = lb[it];
        *reinterpret_cast<u64x2*>(&xsT[row * XS + c * 8]) = v;
      }
    } else if (IND == 2) {
      const float v = xf32[tid];               // read-only input, cached
      xsT[(tid & 1) * XS + (tid >> 1)] = f2bf(v);
    } else {  // IND == 1 (decoder feedback)
      if (tid < 256) xsT[tid] = xf32 ? f2bf(aldf(xf32 + tid)) : (unsigned short)0;
    }
  }
  __syncthreads();
  // ---- Hbuf buf0 = transpose of xsT columns [n0,n0+64): [nl][f] (R13 code) ----
#pragma unroll
  for (int it = 0; it < FP / 8; ++it) {
    const int e = tid + it * 512, f = e >> 6, nl = e & 63;
    Hbuf[nl * HS + f] = xsT[f * XS + n0 + nl];
  }
  __syncthreads();

  f32x4 pacc[2][OT_W];
#pragma unroll
  for (int rt = 0; rt < 2; ++rt)
#pragma unroll
    for (int oi = 0; oi < OT_W; ++oi) pacc[rt][oi] = 0.f;

  auto proj_step = [&](int m, const unsigned short* hb) {
#pragma unroll
    for (int k0 = 0; k0 < FP; k0 += 32) {
      short8 af[2];
#pragma unroll
      for (int rt = 0; rt < 2; ++rt)
        af[rt] = *reinterpret_cast<const short8*>(&hb[(r0 + rt * 16 + l15) * HS + k0 + l4 * 8]);
#pragma unroll
      for (int oi = 0; oi < OT_W; ++oi) {
        const int ot = wc + 4 * oi;
        if (ot < NOT_) {
          short8 bf = *reinterpret_cast<const short8*>(&Wp[(ot * 16 + l15) * KPW + m * FP + k0 + l4 * 8]);
#pragma unroll
          for (int rt = 0; rt < 2; ++rt)
            pacc[rt][oi] = __builtin_amdgcn_mfma_f32_16x16x32_bf16(af[rt], bf, pacc[rt][oi], 0, 0, 0);
        }
      }
    }
  };

  // ---- dbuf loop: {hop(mi) || proj(mi) from buf[mi&1]} -> write buf[(mi+1)&1] -> sync ----
  for (int mi = 0; mi < 4; ++mi) {
    const unsigned short* Am = Amats + mi * 65536;
    f32x4 hacc[2][FT_W];
#pragma unroll
    for (int rt = 0; rt < 2; ++rt)
#pragma unroll
      for (int fi = 0; fi < FT_W; ++fi) hacc[rt][fi] = 0.f;

#pragma unroll
    for (int k0 = 0; k0 < 256; k0 += 32) {
      short8 af[2];
#pragma unroll
      for (int rt = 0; rt < 2; ++rt)
        af[rt] = *reinterpret_cast<const short8*>(&Am[(n0 + r0 + rt * 16 + l15) * 256 + k0 + l4 * 8]);
#pragma unroll
      for (int fi = 0; fi < FT_W; ++fi) {
        const int ft = wc + 4 * fi;
        if (ft < NFT) {
          short8 bf = *reinterpret_cast<const short8*>(&xsT[(ft * 16 + l15) * XS + k0 + l4 * 8]);
#pragma unroll
          for (int rt = 0; rt < 2; ++rt)
            hacc[rt][fi] = __builtin_amdgcn_mfma_f32_16x16x32_bf16(af[rt], bf, hacc[rt][fi], 0, 0, 0);
        }
      }
    }
    proj_step(mi, Hbuf + (mi & 1) * HB);        // reads the buffer hop(mi) does NOT write
    unsigned short* dst = Hbuf + ((mi + 1) & 1) * HB;
#pragma unroll
    for (int fi = 0; fi < FT_W; ++fi) {
      const int ft = wc + 4 * fi;
      if (ft < NFT) {
#pragma unroll
        for (int rt = 0; rt < 2; ++rt)
#pragma unroll
          for (int j = 0; j < 4; ++j)
            dst[(r0 + rt * 16 + l4 * 4 + j) * HS + ft * 16 + l15] = f2bf(hacc[rt][fi][j]);
      }
    }
    __syncthreads();
  }
  proj_step(4, Hbuf);                           // hop3's output is in buf0

  // ---- epilogue ----
  if (MODE == 0) {
    const float br = bias[wc * 16 + l15];
    const float bu = bias[64 + wc * 16 + l15];
#pragma unroll
    for (int rt = 0; rt < 2; ++rt) {
      f32x4 uu;
      ushort4v pk;
#pragma unroll
      for (int jj = 0; jj < 4; ++jj) {
        const float r = 1.f / (1.f + __expf(-(pacc[rt][0][jj] + br)));
        uu[jj] = 1.f / (1.f + __expf(-(pacc[rt][1][jj] + bu)));
        pk[jj] = f2bf(r * hreg[rt][jj]);
      }
      ureg[rt] = uu;
      ast((u64*)(grows + (wc * 16 + l15) * 256 + n0 + r0 + rt * 16 + l4 * 4),
          __builtin_bit_cast(u64, pk));
    }
  } else {
    float* hrow = reinterpret_cast<float*>(Hbuf + HB);  // buf1 overlay (proj4 reads buf0;
                                                        // buf1 fully rewritten by hop0 next stage)
    const float bc = bias[wc * 16 + l15];
#pragma unroll
    for (int rt = 0; rt < 2; ++rt) {
      f32x4 hn;
      ushort4v pk;
#pragma unroll
      for (int jj = 0; jj < 4; ++jj) {
        const float ex = __expf(2.f * (pacc[rt][0][jj] + bc));
        const float c = 1.f - 2.f / (ex + 1.f);     // tanh
        hn[jj] = ureg[rt][jj] * hreg[rt][jj] + (1.f - ureg[rt][jj]) * c;
        pk[jj] = f2bf(hn[jj]);
      }
      hreg[rt] = hn;
      ast((u64*)(grows + (wc * 16 + l15) * 256 + n0 + r0 + rt * 16 + l4 * 4),
          __builtin_bit_cast(u64, pk));
      if (MODE == 2) {
#pragma unroll
        for (int jj = 0; jj < 4; ++jj)
          hrow[(r0 + rt * 16 + l4 * 4 + jj) * 68 + wc * 16 + l15] = hn[jj];
      }
    }
    if (MODE == 2) {
      __syncthreads();
      if (tid < 64) {
        float acc = projB[0];
        const float* hr = hrow + tid * 68;
#pragma unroll
        for (int hid = 0; hid < 64; ++hid) acc = fmaf(hr[hid], projW[hid], acc);
        outp[b * 3072 + n0 + tid] = acc;            // host-read output
        astf(xdout + b * 256 + n0 + tid, acc);      // cross-block feedback
      }
    }
  }
}

// ---------------- persistent main kernel (256 blocks x 512) ----------------
__launch_bounds__(512, 2)
__global__ void dcrnn_main(KP p) {
  __shared__ __align__(16) unsigned short xsT[128 * 264];     // 67584 B
  __shared__ __align__(16) unsigned short Hbuf[2 * 64 * 136]; // 34816 B -> 102400, 1 blk/CU
  const int tid = threadIdx.x;
  const int i = (int)blockIdx.x;
  const int q = (i >> 3) & 3;
  const int b = (i & 7) + 8 * (i >> 5);   // batch's 4 blocks share blockIdx%8 (same XCD)
  const int n0 = q * 64;

  // one-time LDS zero (pads + stale protection for first stage)
  for (int e = tid; e < 128 * 264; e += 512) xsT[e] = 0;
  for (int e = tid; e < 2 * 64 * 136; e += 512) Hbuf[e] = 0;
  __syncthreads();

  unsigned* ctr = p.ctr + b * 64;
  unsigned st = 0;
  auto BAR = [&]() {
    ++st;
    asm volatile("s_waitcnt vmcnt(0)" ::: "memory");  // state stores visible
    __syncthreads();
    if (tid == 0) {
      __hip_atomic_fetch_add(ctr, 1u, __ATOMIC_RELAXED, __HIP_MEMORY_SCOPE_AGENT);
      const unsigned target = st * 4u;
      while (__hip_atomic_load(ctr, __ATOMIC_RELAXED, __HIP_MEMORY_SCOPE_AGENT) < target)
        __builtin_amdgcn_s_sleep(2);
    }
    __syncthreads();
  };

  f32x4 h0[2], h1[2], u[2];
#pragma unroll
  for (int rt = 0; rt < 2; ++rt) { h0[rt] = 0.f; h1[rt] = 0.f; u[rt] = 0.f; }
  int c0 = 0, c1 = 0;

  // ---- encoder ----
  for (int t = 0; t < 12; ++t) {
    const float* x0 = p.enc_in + (b * 12 + t) * 512;
    dc_stage<2, 96, 0, true >(b, n0, tid, x0, nullptr, p.H0[c0] + b * 16384, p.A, p.Wp[0], p.bias[0],
                              h0, u, p.RH0 + b * 16384, nullptr, nullptr, nullptr, nullptr, xsT, Hbuf);
    BAR();
    dc_stage<2, 96, 1, false>(b, n0, tid, x0, nullptr, p.RH0 + b * 16384, p.A, p.Wp[1], p.bias[1],
                              h0, u, p.H0[c0 ^ 1] + b * 16384, nullptr, nullptr, nullptr, nullptr, xsT, Hbuf);
    BAR(); c0 ^= 1;
    dc_stage<64, 128, 0, true >(b, n0, tid, nullptr, p.H0[c0] + b * 16384, p.H1[c1] + b * 16384, p.A, p.Wp[2], p.bias[2],
                                h1, u, p.RH1 + b * 16384, nullptr, nullptr, nullptr, nullptr, xsT, Hbuf);
    BAR();
    dc_stage<64, 128, 1, false>(b, n0, tid, nullptr, p.H0[c0] + b * 16384, p.RH1 + b * 16384, p.A, p.Wp[3], p.bias[3],
                                h1, u, p.H1[c1 ^ 1] + b * 16384, nullptr, nullptr, nullptr, nullptr, xsT, Hbuf);
    BAR(); c1 ^= 1;
  }

  // ---- decoder ----
  for (int t = 0; t < 12; ++t) {
    const float* xd = t ? (p.XD + b * 256) : nullptr;
    dc_stage<1, 96, 0, true >(b, n0, tid, xd, nullptr, p.H0[c0] + b * 16384, p.A, p.Wp[4], p.bias[4],
                              h0, u, p.RH0 + b * 16384, nullptr, nullptr, nullptr, nullptr, xsT, Hbuf);
    BAR();
    dc_stage<1, 96, 1, false>(b, n0, tid, xd, nullptr, p.RH0 + b * 16384, p.A, p.Wp[5], p.bias[5],
                              h0, u, p.H0[c0 ^ 1] + b * 16384, nullptr, nullptr, nullptr, nullptr, xsT, Hbuf);
    BAR(); c0 ^= 1;
    dc_stage<64, 128, 0, true >(b, n0, tid, nullptr, p.H0[c0] + b * 16384, p.H1[c1] + b * 16384, p.A, p.Wp[6], p.bias[6],
                                h1, u, p.RH1 + b * 16384, nullptr, nullptr, nullptr, nullptr, xsT, Hbuf);
    BAR();
    dc_stage<64, 128, 2, false>(b, n0, tid, nullptr, p.H0[c0] + b * 16384, p.RH1 + b * 16384, p.A, p.Wp[7], p.bias[7],
                                h1, u, p.H1[c1 ^ 1] + b * 16384, p.prW, p.prB, p.out + t * 256, p.XD, xsT, Hbuf);
    if (t != 11) BAR();
    c1 ^= 1;
  }
}

// ---------------- host ----------------
extern "C" void kernel_launch(void* const* d_in, const int* in_sizes, int n_in,
                              void* d_out, int out_size, void* d_ws, size_t ws_size,
                              hipStream_t stream)
{
  (void)in_sizes; (void)n_in; (void)out_size; (void)ws_size;
  KP p;
  p.enc_in = (const float*)d_in[0];
  p.sup0 = (const float*)d_in[2];
  p.sup1 = (const float*)d_in[3];
  p.Wsrc[0] = (const float*)d_in[4];  p.bias[0] = (const float*)d_in[5];
  p.Wsrc[1] = (const float*)d_in[6];  p.bias[1] = (const float*)d_in[7];
  p.Wsrc[2] = (const float*)d_in[8];  p.bias[2] = (const float*)d_in[9];
  p.Wsrc[3] = (const float*)d_in[10]; p.bias[3] = (const float*)d_in[11];
  p.Wsrc[4] = (const float*)d_in[12]; p.bias[4] = (const float*)d_in[13];
  p.Wsrc[5] = (const float*)d_in[14]; p.bias[5] = (const float*)d_in[15];
  p.Wsrc[6] = (const float*)d_in[16]; p.bias[6] = (const float*)d_in[17];
  p.Wsrc[7] = (const float*)d_in[18]; p.bias[7] = (const float*)d_in[19];
  p.prW = (const float*)d_in[20];
  p.prB = (const float*)d_in[21];
  p.out = (float*)d_out;

  char* ws = (char*)d_ws;
  size_t off = 0;
  auto carve = [&](size_t bytes) -> char* {
    char* qp = ws + off;
    off += (bytes + 255) & ~(size_t)255;
    return qp;
  };
  p.A = (unsigned short*)carve(4 * 65536 * 2);
  p.Wp[0] = (unsigned short*)carve(128 * 480 * 2);
  p.Wp[1] = (unsigned short*)carve(64 * 480 * 2);
  p.Wp[2] = (unsigned short*)carve(128 * 640 * 2);
  p.Wp[3] = (unsigned short*)carve(64 * 640 * 2);
  p.Wp[4] = (unsigned short*)carve(128 * 480 * 2);
  p.Wp[5] = (unsigned short*)carve(64 * 480 * 2);
  p.Wp[6] = (unsigned short*)carve(128 * 640 * 2);
  p.Wp[7] = (unsigned short*)carve(64 * 640 * 2);
  p.H0[0] = (unsigned short*)carve(64 * 64 * 256 * 2);
  p.H0[1] = (unsigned short*)carve(64 * 64 * 256 * 2);
  p.H1[0] = (unsigned short*)carve(64 * 64 * 256 * 2);
  p.H1[1] = (unsigned short*)carve(64 * 64 * 256 * 2);
  p.RH0 = (unsigned short*)carve(64 * 64 * 256 * 2);
  p.RH1 = (unsigned short*)carve(64 * 64 * 256 * 2);
  p.XD = (float*)carve(64 * 256 * 4);
  p.ctr = (unsigned*)carve(64 * 256);

  prep<<<dim3(512), dim3(256), 0, stream>>>(p);
  dcrnn_main<<<dim3(256), dim3(512), 0, stream>>>(p);
}

// Round 19
// 2280.873 us; speedup vs baseline: 2.5226x; 1.1554x over previous
//
#include <hip/hip_runtime.h>
#include <stdint.h>

// DCRNN forward, MI355X — FINAL: R13 verbatim (measured best: 2278us,
// FETCH 106MB, absmax 2.59e-4).
//  Session conclusion: R13's exact phase structure (stage -> sync -> transpose
//  -> sync -> [hop m -> sync -> proj m -> sync] x4 -> proj4) is itself the
//  L2-locality mechanism — the strict alternation keeps each XCD's 4 blocks
//  in operand-stream lockstep on the shared A/Wp panels. Proven by single-
//  variable tests: phase-split (R16), fused staging (R17), and Hbuf double-
//  buffer alone (R18) each collapse L2 hit rate (FETCH 106 -> 396/458/495MB)
//  and regress ~400us. Geometry (R6/R7/R12/R14), exchange protocol (R8-R11),
//  and cell fusion (R15) also all regress. This is the structural optimum of
//  the persistent-barrier design space explored.
//  - main: 256 blocks x 512 threads = 64 batches x 4 row-quadrants; 84992 B
//    LDS forces 1 block/CU -> all 256 blocks co-resident (deadlock-free
//    barrier by construction). Per-batch 4-block barrier: relaxed agent
//    atomics; batch's blocks share blockIdx%8 -> same XCD L2.
//  - State exchange: 8B agent-scope atomic stores/loads (cache-served).
//  - h/u in MFMA-fragment registers across all 48 cells; cand stages skip
//    re-staging the x-part (persists in xsT); pads zeroed once (xsT only
//    ever holds finite bf16; Wp zero pad columns annihilate stale values).

typedef short short8 __attribute__((ext_vector_type(8)));
typedef float f32x4 __attribute__((ext_vector_type(4)));
typedef unsigned short ushort4v __attribute__((ext_vector_type(4)));
typedef unsigned long long u64;
typedef u64 u64x2 __attribute__((ext_vector_type(2)));

#define DEVI __device__ __forceinline__

DEVI unsigned short f2bf(float x) {
  unsigned int u = __builtin_bit_cast(unsigned int, x);
  u += 0x7FFFu + ((u >> 16) & 1u);  // RNE
  return (unsigned short)(u >> 16);
}
DEVI u64 ald(const u64* p) { return __hip_atomic_load(p, __ATOMIC_RELAXED, __HIP_MEMORY_SCOPE_AGENT); }
DEVI void ast(u64* p, u64 v) { __hip_atomic_store(p, v, __ATOMIC_RELAXED, __HIP_MEMORY_SCOPE_AGENT); }
DEVI float aldf(const float* p) { return __hip_atomic_load(p, __ATOMIC_RELAXED, __HIP_MEMORY_SCOPE_AGENT); }
DEVI void astf(float* p, float v) { __hip_atomic_store(p, v, __ATOMIC_RELAXED, __HIP_MEMORY_SCOPE_AGENT); }

struct KP {
  const float* enc_in;
  const float* sup0; const float* sup1;
  const float* Wsrc[8];
  const float* bias[8];
  const float* prW; const float* prB;
  float* out;
  unsigned short* A;        // [4][256][256] bf16
  unsigned short* Wp[8];    // packed [O][5*FP] bf16
  unsigned short* H0[2];    // [64 b][64 f][256 n] bf16 rows, ping-pong
  unsigned short* H1[2];
  unsigned short* RH0;      // r*h rows
  unsigned short* RH1;
  float* XD;                // [64][256] decoder feedback
  unsigned* ctr;            // 64 per-batch counters, 256B apart
};

// ---------------- prep kernel (512 blocks x 256) ----------------
__global__ void prep(KP p) {
  const int i = blockIdx.x, tid = threadIdx.x;
  {  // A matrices
    const int s = i & 1, r = i >> 1;
    const float* S = s ? p.sup1 : p.sup0;
    float acc = 0.f;
    for (int k = 0; k < 256; ++k) acc = fmaf(S[r * 256 + k], S[k * 256 + tid], acc);
    p.A[(2 * s + 0) * 65536 + r * 256 + tid] = f2bf(S[r * 256 + tid]);
    p.A[(2 * s + 1) * 65536 + r * 256 + tid] = f2bf(2.f * acc - (r == tid ? 1.f : 0.f));
  }
  {  // packed weights: Wp[o][m*FP+f] = W[f,m,o], f zero-padded to FP
    const int gtid = i * 256 + tid;
    const int Fs[8]  = {66, 66, 128, 128, 65, 65, 128, 128};
    const int Os[8]  = {128, 64, 128, 64, 128, 64, 128, 64};
    const int FPs[8] = {96, 96, 128, 128, 96, 96, 128, 128};
    for (int w = 0; w < 8; ++w) {
      const int FPw = FPs[w], KPw = 5 * FPw, tot = Os[w] * KPw;
      for (int e = gtid; e < tot; e += 512 * 256) {
        const int o = e / KPw, k2 = e - o * KPw, m = k2 / FPw, f = k2 - m * FPw;
        p.Wp[w][e] = f2bf((f < Fs[w]) ? p.Wsrc[w][(f * 5 + m) * Os[w] + o] : 0.f);
      }
    }
  }
  {  // zero initial hidden via agent-scope stores
    const int gtid = i * 256 + tid;
    u64* z0 = (u64*)p.H0[0];
    u64* z1 = (u64*)p.H1[0];
    ast(z0 + 2 * gtid, 0); ast(z0 + 2 * gtid + 1, 0);
    ast(z1 + 2 * gtid, 0); ast(z1 + 2 * gtid + 1, 0);
  }
  if (i == 0 && tid < 64)
    __hip_atomic_store(p.ctr + tid * 64, 0u, __ATOMIC_RELAXED, __HIP_MEMORY_SCOPE_AGENT);
}

// ---------------- fused diffusion-conv stage (R13 protocol) ----------------
// MODE 0: gates (O=128, sigmoid; writes RH rows, u regs)
// MODE 1: cand  (O=64, tanh; GRU update of hreg; writes H rows)
// MODE 2: MODE1 + final projection (writes out slice and XD)
// XSTAGE: stage the x-part into xsT (gates). Cand stages skip it — xsT is
// untouched between a cell's gates and cand stages, so the x-part persists.
template<int IND, int FP, int MODE, bool XSTAGE>
DEVI void dc_stage(int b, int n0, int tid,
                   const float* xf32,             // IND<=2 x input (IND==1 via agent ld)
                   const unsigned short* xbf,     // IND==64 bf16 rows [64][256]
                   const unsigned short* hrows,   // bf16 rows [64][256] (h or r*h)
                   const unsigned short* Amats,
                   const unsigned short* Wp, const float* bias,
                   f32x4 (&hreg)[2], f32x4 (&ureg)[2],
                   unsigned short* grows,         // output rows (RH or Hnew)
                   const float* projW, const float* projB,
                   float* outp, float* xdout,
                   unsigned short* xsT, unsigned short* Hbuf)
{
  constexpr int O = (MODE == 0) ? 128 : 64;
  constexpr int KPW = 5 * FP;
  constexpr int XS = 264;            // xsT row stride (bf16 elems)
  constexpr int HS = 136;            // Hbuf row stride
  constexpr int NFT = FP / 16;
  constexpr int NOT_ = O / 16;
  constexpr int FT_W = (NFT + 3) / 4;
  constexpr int OT_W = (NOT_ + 3) / 4;

  const int wv8 = tid >> 6, ln = tid & 63;
  const int l15 = ln & 15, l4 = ln >> 4;
  const int wr = wv8 & 1, wc = wv8 >> 1;   // row-half / tile-column quarter
  const int r0 = wr * 32;

  // ---- build xsT [f][n]: h-part always; x-part only when XSTAGE ----
  {
    u64 la[4], lb[4];
    const u64* src = (const u64*)hrows;
#pragma unroll
    for (int it = 0; it < 4; ++it) {
      const int g = tid + it * 512;
      la[it] = ald(src + 2 * g); lb[it] = ald(src + 2 * g + 1);
    }
#pragma unroll
    for (int it = 0; it < 4; ++it) {
      const int g = tid + it * 512, row = g >> 5, c = g & 31;
      u64x2 v; v[0] = la[it]; v[1] = lb[it];
      *reinterpret_cast<u64x2*>(&xsT[(IND + row) * XS + c * 8]) = v;
    }
  }
  if (XSTAGE) {
    if (IND == 64) {
      u64 la[4], lb[4];
      const u64* src = (const u64*)xbf;
#pragma unroll
      for (int it = 0; it < 4; ++it) {
        const int g = tid + it * 512;
        la[it] = ald(src + 2 * g); lb[it] = ald(src + 2 * g + 1);
      }
#pragma unroll
      for (int it = 0; it < 4; ++it) {
        const int g = tid + it * 512, row = g >> 5, c = g & 31;
        u64x2 v; v[0] = la[it]; v[1] = lb[it];
        *reinterpret_cast<u64x2*>(&xsT[row * XS + c * 8]) = v;
      }
    } else if (IND == 2) {
      const float v = xf32[tid];               // read-only input, cached
      xsT[(tid & 1) * XS + (tid >> 1)] = f2bf(v);
    } else {  // IND == 1 (decoder feedback)
      if (tid < 256) xsT[tid] = xf32 ? f2bf(aldf(xf32 + tid)) : (unsigned short)0;
    }
  }
  // pads [IND+64, FP): zeroed once in prologue; between stages xsT only ever
  // holds finite bf16, and Wp's zero pad columns annihilate stale values.
  __syncthreads();
  // ---- Hbuf = transpose of xsT columns [n0,n0+64): [nl][f] ----
#pragma unroll
  for (int it = 0; it < FP / 8; ++it) {
    const int e = tid + it * 512, f = e >> 6, nl = e & 63;
    Hbuf[nl * HS + f] = xsT[f * XS + n0 + nl];
  }
  __syncthreads();

  f32x4 pacc[2][OT_W];
#pragma unroll
  for (int rt = 0; rt < 2; ++rt)
#pragma unroll
    for (int oi = 0; oi < OT_W; ++oi) pacc[rt][oi] = 0.f;

  auto proj_step = [&](int m) {
#pragma unroll
    for (int k0 = 0; k0 < FP; k0 += 32) {
      short8 af[2];
#pragma unroll
      for (int rt = 0; rt < 2; ++rt)
        af[rt] = *reinterpret_cast<const short8*>(&Hbuf[(r0 + rt * 16 + l15) * HS + k0 + l4 * 8]);
#pragma unroll
      for (int oi = 0; oi < OT_W; ++oi) {
        const int ot = wc + 4 * oi;
        if (ot < NOT_) {
          short8 bf = *reinterpret_cast<const short8*>(&Wp[(ot * 16 + l15) * KPW + m * FP + k0 + l4 * 8]);
#pragma unroll
          for (int rt = 0; rt < 2; ++rt)
            pacc[rt][oi] = __builtin_amdgcn_mfma_f32_16x16x32_bf16(af[rt], bf, pacc[rt][oi], 0, 0, 0);
        }
      }
    }
  };

  proj_step(0);  // identity slice

  for (int mi = 0; mi < 4; ++mi) {
    const unsigned short* Am = Amats + mi * 65536;
    f32x4 hacc[2][FT_W];
#pragma unroll
    for (int rt = 0; rt < 2; ++rt)
#pragma unroll
      for (int fi = 0; fi < FT_W; ++fi) hacc[rt][fi] = 0.f;

#pragma unroll
    for (int k0 = 0; k0 < 256; k0 += 32) {
      short8 af[2];
#pragma unroll
      for (int rt = 0; rt < 2; ++rt)
        af[rt] = *reinterpret_cast<const short8*>(&Am[(n0 + r0 + rt * 16 + l15) * 256 + k0 + l4 * 8]);
#pragma unroll
      for (int fi = 0; fi < FT_W; ++fi) {
        const int ft = wc + 4 * fi;
        if (ft < NFT) {
          short8 bf = *reinterpret_cast<const short8*>(&xsT[(ft * 16 + l15) * XS + k0 + l4 * 8]);
#pragma unroll
          for (int rt = 0; rt < 2; ++rt)
            hacc[rt][fi] = __builtin_amdgcn_mfma_f32_16x16x32_bf16(af[rt], bf, hacc[rt][fi], 0, 0, 0);
        }
      }
    }
    __syncthreads();   // previous proj_step readers of Hbuf done
#pragma unroll
    for (int fi = 0; fi < FT_W; ++fi) {
      const int ft = wc + 4 * fi;
      if (ft < NFT) {
#pragma unroll
        for (int rt = 0; rt < 2; ++rt)
#pragma unroll
          for (int j = 0; j < 4; ++j)
            Hbuf[(r0 + rt * 16 + l4 * 4 + j) * HS + ft * 16 + l15] = f2bf(hacc[rt][fi][j]);
      }
    }
    __syncthreads();
    proj_step(mi + 1);
  }

  // ---- epilogue ----
  if (MODE == 0) {
    const float br = bias[wc * 16 + l15];
    const float bu = bias[64 + wc * 16 + l15];
#pragma unroll
    for (int rt = 0; rt < 2; ++rt) {
      f32x4 uu;
      ushort4v pk;
#pragma unroll
      for (int jj = 0; jj < 4; ++jj) {
        const float r = 1.f / (1.f + __expf(-(pacc[rt][0][jj] + br)));
        uu[jj] = 1.f / (1.f + __expf(-(pacc[rt][1][jj] + bu)));
        pk[jj] = f2bf(r * hreg[rt][jj]);
      }
      ureg[rt] = uu;
      ast((u64*)(grows + (wc * 16 + l15) * 256 + n0 + r0 + rt * 16 + l4 * 4),
          __builtin_bit_cast(u64, pk));
    }
  } else {
    float* hrow = reinterpret_cast<float*>(Hbuf);   // [64][68] fp32 overlay
    if (MODE == 2) __syncthreads();                 // proj(4) readers done
    const float bc = bias[wc * 16 + l15];
#pragma unroll
    for (int rt = 0; rt < 2; ++rt) {
      f32x4 hn;
      ushort4v pk;
#pragma unroll
      for (int jj = 0; jj < 4; ++jj) {
        const float ex = __expf(2.f * (pacc[rt][0][jj] + bc));
        const float c = 1.f - 2.f / (ex + 1.f);     // tanh
        hn[jj] = ureg[rt][jj] * hreg[rt][jj] + (1.f - ureg[rt][jj]) * c;
        pk[jj] = f2bf(hn[jj]);
      }
      hreg[rt] = hn;
      ast((u64*)(grows + (wc * 16 + l15) * 256 + n0 + r0 + rt * 16 + l4 * 4),
          __builtin_bit_cast(u64, pk));
      if (MODE == 2) {
#pragma unroll
        for (int jj = 0; jj < 4; ++jj)
          hrow[(r0 + rt * 16 + l4 * 4 + jj) * 68 + wc * 16 + l15] = hn[jj];
      }
    }
    if (MODE == 2) {
      __syncthreads();
      if (tid < 64) {
        float acc = projB[0];
        const float* hr = hrow + tid * 68;
#pragma unroll
        for (int hid = 0; hid < 64; ++hid) acc = fmaf(hr[hid], projW[hid], acc);
        outp[b * 3072 + n0 + tid] = acc;            // host-read output
        astf(xdout + b * 256 + n0 + tid, acc);      // cross-block feedback
      }
    }
  }
}

// ---------------- persistent main kernel (256 blocks x 512) ----------------
__launch_bounds__(512, 2)
__global__ void dcrnn_main(KP p) {
  __shared__ __align__(16) unsigned short xsT[128 * 264];   // 67584 B
  __shared__ __align__(16) unsigned short Hbuf[64 * 136];   // 17408 B -> 84992 total, 1 blk/CU
  const int tid = threadIdx.x;
  const int i = (int)blockIdx.x;
  const int q = (i >> 3) & 3;
  const int b = (i & 7) + 8 * (i >> 5);   // batch's 4 blocks share blockIdx%8 (same XCD)
  const int n0 = q * 64;

  // one-time LDS zero (pads + NaN-pattern protection for first stage)
  for (int e = tid; e < 128 * 264; e += 512) xsT[e] = 0;
  for (int e = tid; e < 64 * 136; e += 512) Hbuf[e] = 0;
  __syncthreads();

  unsigned* ctr = p.ctr + b * 64;
  unsigned st = 0;
  auto BAR = [&]() {
    ++st;
    asm volatile("s_waitcnt vmcnt(0)" ::: "memory");  // state stores visible
    __syncthreads();
    if (tid == 0) {
      __hip_atomic_fetch_add(ctr, 1u, __ATOMIC_RELAXED, __HIP_MEMORY_SCOPE_AGENT);
      const unsigned target = st * 4u;
      while (__hip_atomic_load(ctr, __ATOMIC_RELAXED, __HIP_MEMORY_SCOPE_AGENT) < target)
        __builtin_amdgcn_s_sleep(2);
    }
    __syncthreads();
  };

  f32x4 h0[2], h1[2], u[2];
#pragma unroll
  for (int rt = 0; rt < 2; ++rt) { h0[rt] = 0.f; h1[rt] = 0.f; u[rt] = 0.f; }
  int c0 = 0, c1 = 0;

  // ---- encoder ----
  for (int t = 0; t < 12; ++t) {
    const float* x0 = p.enc_in + (b * 12 + t) * 512;
    dc_stage<2, 96, 0, true >(b, n0, tid, x0, nullptr, p.H0[c0] + b * 16384, p.A, p.Wp[0], p.bias[0],
                              h0, u, p.RH0 + b * 16384, nullptr, nullptr, nullptr, nullptr, xsT, Hbuf);
    BAR();
    dc_stage<2, 96, 1, false>(b, n0, tid, x0, nullptr, p.RH0 + b * 16384, p.A, p.Wp[1], p.bias[1],
                              h0, u, p.H0[c0 ^ 1] + b * 16384, nullptr, nullptr, nullptr, nullptr, xsT, Hbuf);
    BAR(); c0 ^= 1;
    dc_stage<64, 128, 0, true >(b, n0, tid, nullptr, p.H0[c0] + b * 16384, p.H1[c1] + b * 16384, p.A, p.Wp[2], p.bias[2],
                                h1, u, p.RH1 + b * 16384, nullptr, nullptr, nullptr, nullptr, xsT, Hbuf);
    BAR();
    dc_stage<64, 128, 1, false>(b, n0, tid, nullptr, p.H0[c0] + b * 16384, p.RH1 + b * 16384, p.A, p.Wp[3], p.bias[3],
                                h1, u, p.H1[c1 ^ 1] + b * 16384, nullptr, nullptr, nullptr, nullptr, xsT, Hbuf);
    BAR(); c1 ^= 1;
  }

  // ---- decoder ----
  for (int t = 0; t < 12; ++t) {
    const float* xd = t ? (p.XD + b * 256) : nullptr;
    dc_stage<1, 96, 0, true >(b, n0, tid, xd, nullptr, p.H0[c0] + b * 16384, p.A, p.Wp[4], p.bias[4],
                              h0, u, p.RH0 + b * 16384, nullptr, nullptr, nullptr, nullptr, xsT, Hbuf);
    BAR();
    dc_stage<1, 96, 1, false>(b, n0, tid, xd, nullptr, p.RH0 + b * 16384, p.A, p.Wp[5], p.bias[5],
                              h0, u, p.H0[c0 ^ 1] + b * 16384, nullptr, nullptr, nullptr, nullptr, xsT, Hbuf);
    BAR(); c0 ^= 1;
    dc_stage<64, 128, 0, true >(b, n0, tid, nullptr, p.H0[c0] + b * 16384, p.H1[c1] + b * 16384, p.A, p.Wp[6], p.bias[6],
                                h1, u, p.RH1 + b * 16384, nullptr, nullptr, nullptr, nullptr, xsT, Hbuf);
    BAR();
    dc_stage<64, 128, 2, false>(b, n0, tid, nullptr, p.H0[c0] + b * 16384, p.RH1 + b * 16384, p.A, p.Wp[7], p.bias[7],
                                h1, u, p.H1[c1 ^ 1] + b * 16384, p.prW, p.prB, p.out + t * 256, p.XD, xsT, Hbuf);
    if (t != 11) BAR();
    c1 ^= 1;
  }
}

// ---------------- host ----------------
extern "C" void kernel_launch(void* const* d_in, const int* in_sizes, int n_in,
                              void* d_out, int out_size, void* d_ws, size_t ws_size,
                              hipStream_t stream)
{
  (void)in_sizes; (void)n_in; (void)out_size; (void)ws_size;
  KP p;
  p.enc_in = (const float*)d_in[0];
  p.sup0 = (const float*)d_in[2];
  p.sup1 = (const float*)d_in[3];
  p.Wsrc[0] = (const float*)d_in[4];  p.bias[0] = (const float*)d_in[5];
  p.Wsrc[1] = (const float*)d_in[6];  p.bias[1] = (const float*)d_in[7];
  p.Wsrc[2] = (const float*)d_in[8];  p.bias[2] = (const float*)d_in[9];
  p.Wsrc[3] = (const float*)d_in[10]; p.bias[3] = (const float*)d_in[11];
  p.Wsrc[4] = (const float*)d_in[12]; p.bias[4] = (const float*)d_in[13];
  p.Wsrc[5] = (const float*)d_in[14]; p.bias[5] = (const float*)d_in[15];
  p.Wsrc[6] = (const float*)d_in[16]; p.bias[6] = (const float*)d_in[17];
  p.Wsrc[7] = (const float*)d_in[18]; p.bias[7] = (const float*)d_in[19];
  p.prW = (const float*)d_in[20];
  p.prB = (const float*)d_in[21];
  p.out = (float*)d_out;

  char* ws = (char*)d_ws;
  size_t off = 0;
  auto carve = [&](size_t bytes) -> char* {
    char* qp = ws + off;
    off += (bytes + 255) & ~(size_t)255;
    return qp;
  };
  p.A = (unsigned short*)carve(4 * 65536 * 2);
  p.Wp[0] = (unsigned short*)carve(128 * 480 * 2);
  p.Wp[1] = (unsigned short*)carve(64 * 480 * 2);
  p.Wp[2] = (unsigned short*)carve(128 * 640 * 2);
  p.Wp[3] = (unsigned short*)carve(64 * 640 * 2);
  p.Wp[4] = (unsigned short*)carve(128 * 480 * 2);
  p.Wp[5] = (unsigned short*)carve(64 * 480 * 2);
  p.Wp[6] = (unsigned short*)carve(128 * 640 * 2);
  p.Wp[7] = (unsigned short*)carve(64 * 640 * 2);
  p.H0[0] = (unsigned short*)carve(64 * 64 * 256 * 2);
  p.H0[1] = (unsigned short*)carve(64 * 64 * 256 * 2);
  p.H1[0] = (unsigned short*)carve(64 * 64 * 256 * 2);
  p.H1[1] = (unsigned short*)carve(64 * 64 * 256 * 2);
  p.RH0 = (unsigned short*)carve(64 * 64 * 256 * 2);
  p.RH1 = (unsigned short*)carve(64 * 64 * 256 * 2);
  p.XD = (float*)carve(64 * 256 * 4);
  p.ctr = (unsigned*)carve(64 * 256);

  prep<<<dim3(512), dim3(256), 0, stream>>>(p);
  dcrnn_main<<<dim3(256), dim3(512), 0, stream>>>(p);
}